// Round 23
// baseline (170.220 us; speedup 1.0000x reference)
//
#include <hip/hip_runtime.h>
#include <stdint.h>
#include <math.h>

typedef int v4i  __attribute__((ext_vector_type(4)));
typedef int v16i __attribute__((ext_vector_type(16)));
typedef short v8s __attribute__((ext_vector_type(8)));

#define NIMG 16
#define NCH  256
#define HW   3136          // 56*56
#define NPIX 50176         // 16*3136
#define PADH 58
#define NKT  72            // 2304/32
#define NCOT 8             // 256/32
#define WELEMS 589824      // 256*256*3*3

// workspace layout (bytes)
#define A0_OFF   0
#define A0_BYTES (16*58*58*256)          // 13,778,944 padded NHWC int8 acts
#define WP0_OFF  (A0_OFF + A0_BYTES)
#define WP_BYTES (NKT*NCOT*64*16)        // 589,824 packed weight frags
#define WP1_OFF  (WP0_OFF + WP_BYTES)
#define COEF_OFF (WP1_OFF + WP_BYTES)    // floats A0[256] B0[256] scales[2]
#define MAXW_OFF (COEF_OFF + 4352)       // 2 x u32   (zeroed by 4KB memset)
#define SUM1_OFF (MAXW_OFF + 32)         // 512 x u64 (zeroed by 4KB memset)
#define PART_OFF (SUM1_OFF + 4096)       // 4096 x double2 (bn0 per-plane partials)
#define CQ_OFF   15032832                // 256-aligned; optional int16 Cout here
#define CQ_BYTES ((size_t)NPIX*256*2)    // 25,690,112

// aux1: blocks 0..4095 = bn0 per-plane partial sums; blocks 4096..4607 = wmax
__global__ __launch_bounds__(256) void aux1(const float* __restrict__ X,
        double2* __restrict__ part, const float* __restrict__ W0,
        const float* __restrict__ W1, unsigned* __restrict__ maxw) {
    int b = blockIdx.x;
    int tid = threadIdx.x;
    if (b < 4096) {
        const float4* src = (const float4*)(X + (size_t)b * HW);
        double s = 0.0, s2 = 0.0;
        for (int i = tid; i < HW / 4; i += 256) {
            float4 v = src[i];
            s  += (double)v.x + (double)v.y + (double)v.z + (double)v.w;
            s2 += (double)v.x * (double)v.x + (double)v.y * (double)v.y
                + (double)v.z * (double)v.z + (double)v.w * (double)v.w;
        }
        #pragma unroll
        for (int off = 32; off; off >>= 1) {
            s  += __shfl_xor(s, off);
            s2 += __shfl_xor(s2, off);
        }
        __shared__ double sh[8];
        int wave = tid >> 6, lane = tid & 63;
        if (lane == 0) { sh[wave * 2] = s; sh[wave * 2 + 1] = s2; }
        __syncthreads();
        if (tid == 0) {
            double2 o; o.x = sh[0] + sh[2] + sh[4] + sh[6];
            o.y = sh[1] + sh[3] + sh[5] + sh[7];
            part[b] = o;
        }
    } else {
        int wb = b - 4096;                 // 0..511
        int ten = wb >> 8, blk = wb & 255;
        const float* Wt = ten ? W1 : W0;
        __shared__ float sh[256];
        float m = 0.f;
        for (int i = blk * 256 + tid; i < WELEMS; i += 256 * 256)
            m = fmaxf(m, fabsf(Wt[i]));
        sh[tid] = m; __syncthreads();
        for (int o = 128; o > 0; o >>= 1) {
            if (tid < o) sh[tid] = fmaxf(sh[tid], sh[tid + o]);
            __syncthreads();
        }
        if (tid == 0) atomicMax(&maxw[ten], __float_as_uint(sh[0]));
    }
}

// aux2: block 0 = bn0 finalize; blocks 1..256 = weight quant+pack (TAP-MAJOR,
// matching the conv: k = tap*256 + ci; Wpack[kt][cot][lane][16])
__global__ __launch_bounds__(256) void aux2(const double2* __restrict__ part,
        const float* __restrict__ g, const float* __restrict__ bb,
        const float* __restrict__ W0, const float* __restrict__ W1,
        const unsigned* __restrict__ maxwBits, float* __restrict__ A0,
        float* __restrict__ B0, int8_t* __restrict__ D0, int8_t* __restrict__ D1,
        float* __restrict__ scales) {
    int b = blockIdx.x;
    int tid = threadIdx.x;
    if (b == 0) {
        int c = tid;
        double s = 0.0, s2 = 0.0;
        for (int n = 0; n < NIMG; ++n) {
            double2 v = part[n * 256 + c];
            s += v.x; s2 += v.y;
        }
        double mean = s / (double)NPIX;
        double var  = s2 / (double)NPIX - mean * mean;
        float meanf = (float)mean, varf = (float)var;
        float rstd = (float)(1.0 / sqrt((double)varf + 1e-5));
        float gc = g[c], bc = bb[c];
        A0[c] = rstd * gc;
        B0[c] = bc - meanf * rstd * gc;
    } else {
        int wb = b - 1;                    // 0..255
        int ten = wb >> 7, blk = wb & 127;
        const float* Wt = ten ? W1 : W0;
        int8_t* dst = ten ? D1 : D0;
        float maxw = tanhf(__uint_as_float(maxwBits[ten]));
        if (blk == 0 && tid == 0) scales[ten] = maxw / 225.f;
        float twoM = 2.f * maxw;
        for (int e = blk * 256 + tid; e < WELEMS; e += 128 * 256) {
            int o = e / 2304, rem = e % 2304;
            int ci = rem / 9, tap = rem % 9;
            float t = tanhf(Wt[e]);
            float wn = t / twoM + 0.5f;
            int r = (int)rintf(wn * 15.f);
            int q = 2 * r - 15;
            int k = tap * 256 + ci;        // tap-major conv layout
            int kt = k >> 5, k5 = k & 31;
            int lane = ((k5 >> 4) << 5) | (o & 31);
            int j = k5 & 15;
            dst[((((size_t)kt * NCOT + (o >> 5)) * 64 + lane) << 4) | j] = (int8_t)q;
        }
    }
}

// quantize BN0(x) -> padded NHWC int8 via LDS transpose; one block per (n,h).
// Also writes the pad halo zeros (replaces the 13.8MB memset).
__global__ __launch_bounds__(256) void quant0(const float* __restrict__ X,
        const float* __restrict__ A0, const float* __restrict__ B0,
        int8_t* __restrict__ Apad) {
    __shared__ int8_t tile[56 * 260];     // stride 260: conflict-free byte columns
    int h = blockIdx.x, n = blockIdx.y;
    int tid = threadIdx.x;
    const float4* src4 = (const float4*)X;
    for (int i = tid; i < 256 * 14; i += 256) {
        int c = i / 14, q = i - c * 14;
        float4 v = src4[((size_t)(n * 256 + c) * HW + h * 56) / 4 + q];
        float ac = A0[c], bc = B0[c];
        float vv[4] = {v.x, v.y, v.z, v.w};
        #pragma unroll
        for (int j = 0; j < 4; ++j) {
            float y = fmaf(vv[j], ac, bc);
            y = fminf(fmaxf(y, 0.f), 1.f);
            tile[(q * 4 + j) * 260 + c] = (int8_t)(int)rintf(y * 15.f);
        }
    }
    // halo zeroing (independent of tile)
    if (h == 0) {
        unsigned* r0  = (unsigned*)(Apad + ((size_t)n * PADH + 0) * PADH * 256);
        unsigned* r57 = (unsigned*)(Apad + (((size_t)n * PADH + 57) * PADH) * 256);
        for (int i = tid; i < 58 * 64; i += 256) { r0[i] = 0u; r57[i] = 0u; }
    }
    {
        unsigned* c0p  = (unsigned*)(Apad + (((size_t)n * PADH + h + 1) * PADH + 0) * 256);
        unsigned* c57p = (unsigned*)(Apad + (((size_t)n * PADH + h + 1) * PADH + 57) * 256);
        if (tid < 64) c0p[tid] = 0u;
        else if (tid < 128) c57p[tid - 64] = 0u;
    }
    __syncthreads();
    unsigned* dst = (unsigned*)(Apad + (((size_t)n * PADH + h + 1) * PADH + 1) * 256);
    for (int i = tid; i < 56 * 64; i += 256) {
        int w = i >> 6, c4 = (i & 63) << 2;
        dst[w * 64 + (c4 >> 2)] = *(const unsigned*)&tile[w * 260 + c4];
    }
}

typedef __attribute__((address_space(1))) const unsigned int gu32;
typedef __attribute__((address_space(3))) unsigned int lu32;
__device__ __forceinline__ void gll16(const void* g, void* l) {
    __builtin_amdgcn_global_load_lds((gu32*)g, (lu32*)l, 16, 0, 0);
}

// wave w stages its own two 1KB weight chunks (cout-tiles c0, c1) of K-step ktn
__device__ __forceinline__ void stageW(const char* wgb, char* ldsbuf,
        int ktn, int c0, int c1, int lane) {
    const char* src = wgb + (size_t)ktn * 8192;
    gll16(src + c0 * 1024 + lane * 16, ldsbuf + c0 * 1024 + lane * 16);
    gll16(src + c1 * 1024 + lane * 16, ldsbuf + c1 * 1024 + lane * 16);
}

// conv0: standalone (no template coupling). Block: 4 waves, 2 image rows x
// 256 couts; barrier-free K-loop, per-wave weight chunk ownership, vmcnt(2).
// Epilogue: int16 Cout ((s+8)>>4) + fused exact int64 bn1 stats.
__global__ __launch_bounds__(256, 2) void conv0_mfma(const int8_t* __restrict__ A,
        const v4i* __restrict__ Wp, short* __restrict__ Cout,
        unsigned long long* __restrict__ sums) {
    __shared__ v4i actT[16 * 233];        // 59.6 KB, read-only after prologue
    __shared__ v4i wbuf[2][512];          // 2 x 8 KB, per-wave chunk ownership
    int tid = threadIdx.x;
    int lane = tid & 63, wave = tid >> 6;
    int rp = blockIdx.x, n = blockIdx.y;
    int y0 = rp * 2;
    int l31 = lane & 31, half = lane >> 5;

    const int8_t* asrc = A + (((size_t)n * PADH + y0) * PADH) * 256;
    for (int i = tid; i < 4 * 58 * 16; i += 256) {
        int rr = i / (58 * 16);
        int rem = i - rr * (58 * 16);
        int px = rem >> 4, hh = rem & 15;
        v4i v = *(const v4i*)(asrc + ((size_t)rr * PADH + px) * 256 + hh * 16);
        actT[hh * 233 + rr * 58 + px] = v;
    }
    __syncthreads();   // actT read-only from here

    int c0 = wave, c1 = wave + 4;
    const char* wgb = (const char*)Wp;
    stageW(wgb, (char*)&wbuf[0][0], 0, c0, c1, lane);   // W[0], own chunks

    int pidx[4];
    #pragma unroll
    for (int m = 0; m < 4; ++m) {
        int s = m * 32 + l31;
        int rr = s >> 6, col = s & 63;
        int xx = col < 56 ? col : 55;
        pidx[m] = (rr + 1) * 58 + xx + 1;
    }

    v16i acc[8] = {};

    int kt = 0;
    #pragma unroll 1
    for (int dyi = 0; dyi < 3; ++dyi) {
        #pragma unroll
        for (int dxi = 0; dxi < 3; ++dxi) {
            int doff = dyi * 58 + dxi - 59;
            #pragma unroll
            for (int kk = 0; kk < 8; ++kk) {
                int ktn = kt + 1; if (ktn > 71) ktn = 71;
                stageW(wgb, (char*)&wbuf[ktn & 1][0], ktn, c0, c1, lane);
                asm volatile("s_waitcnt vmcnt(2)" ::: "memory");
                const v4i* wb = &wbuf[kt & 1][0];
                int hb = (kk * 2 + half) * 233 + doff;
                v4i wf0 = wb[c0 * 64 + lane];
                v4i wf1 = wb[c1 * 64 + lane];
                v4i af0 = actT[hb + pidx[0]];
                v4i af1 = actT[hb + pidx[1]];
                v4i af2 = actT[hb + pidx[2]];
                v4i af3 = actT[hb + pidx[3]];
                acc[0] = __builtin_amdgcn_mfma_i32_32x32x32_i8(af0, wf0, acc[0], 0, 0, 0);
                acc[1] = __builtin_amdgcn_mfma_i32_32x32x32_i8(af1, wf0, acc[1], 0, 0, 0);
                acc[2] = __builtin_amdgcn_mfma_i32_32x32x32_i8(af2, wf0, acc[2], 0, 0, 0);
                acc[3] = __builtin_amdgcn_mfma_i32_32x32x32_i8(af3, wf0, acc[3], 0, 0, 0);
                acc[4] = __builtin_amdgcn_mfma_i32_32x32x32_i8(af0, wf1, acc[4], 0, 0, 0);
                acc[5] = __builtin_amdgcn_mfma_i32_32x32x32_i8(af1, wf1, acc[5], 0, 0, 0);
                acc[6] = __builtin_amdgcn_mfma_i32_32x32x32_i8(af2, wf1, acc[6], 0, 0, 0);
                acc[7] = __builtin_amdgcn_mfma_i32_32x32x32_i8(af3, wf1, acc[7], 0, 0, 0);
                ++kt;
            }
        }
    }
    asm volatile("s_waitcnt vmcnt(0)" ::: "memory");

    int pbase = n * HW + y0 * 56;
    #pragma unroll
    for (int ci = 0; ci < 2; ++ci) {
        int co = (wave + ci * 4) * 32 + l31;
        long long ssum = 0, ssq = 0;
        #pragma unroll
        for (int m = 0; m < 4; ++m) {
            v16i a = acc[ci * 4 + m];
            #pragma unroll
            for (int r = 0; r < 16; ++r) {
                int prow = (r & 3) + ((r >> 2) << 3) + (half << 2);
                int s = m * 32 + prow;
                int rr = s >> 6, col = s & 63;
                if (col < 56) {
                    Cout[(size_t)(pbase + rr * 56 + col) * 256 + co] =
                        (short)((a[r] + 8) >> 4);
                    ssum += a[r];
                    ssq  += (long long)a[r] * a[r];
                }
            }
        }
        ssum += __shfl_xor(ssum, 32);
        ssq  += __shfl_xor(ssq, 32);
        if (half == 0) {
            atomicAdd(&sums[co], (unsigned long long)ssum);
            atomicAdd(&sums[256 + co], (unsigned long long)ssq);
        }
    }
}

// conv1 fused: reads int16 Cout directly, computes BN1 affine per block from
// exact sums, quantizes inline during act staging. Coeffs in padded [16][17]
// LDS (bank stride 17 -> staging reads conflict-free).
__global__ __launch_bounds__(256, 2) void conv1_fused(const short* __restrict__ CinQ,
        const v4i* __restrict__ Wp, const unsigned long long* __restrict__ sums,
        const float* __restrict__ g, const float* __restrict__ bb,
        const float* __restrict__ scales, const float* __restrict__ Xin,
        float* __restrict__ Out) {
    __shared__ v4i actT[16 * 233];
    __shared__ v4i wbuf[2][512];
    __shared__ float a1s[16][17], b1s[16][17];   // +1 pad: conflict-free
    int tid = threadIdx.x;
    int lane = tid & 63, wave = tid >> 6;
    int rp = blockIdx.x, n = blockIdx.y;
    int y0 = rp * 2;
    int l31 = lane & 31, half = lane >> 5;

    float s1 = scales[1];

    {   // per-block BN1 coeff compute from exact int64 sums
        int c = tid;
        double sc0 = (double)scales[0];
        double S  = (double)(long long)sums[c];
        double S2 = (double)(long long)sums[256 + c];
        double meanS = S / (double)NPIX;
        double varS  = S2 / (double)NPIX - meanS * meanS;
        float meanf = (float)(sc0 * meanS);
        float varf  = (float)(sc0 * sc0 * varS);
        float rstd = (float)(1.0 / sqrt((double)varf + 1e-5));
        float gc = g[c], bc = bb[c];
        a1s[c >> 4][c & 15] = (float)(sc0 * (double)rstd * (double)gc * 16.0);
        b1s[c >> 4][c & 15] = bc - meanf * rstd * gc;
    }
    __syncthreads();
    for (int i = tid; i < 4 * 58 * 16; i += 256) {
        int rr = i / (58 * 16);
        int rem = i - rr * (58 * 16);
        int px = rem >> 4, hh = rem & 15;
        int irow = y0 + rr - 1, ix = px - 1;
        v4i v = {0, 0, 0, 0};
        if ((unsigned)irow < 56u && (unsigned)ix < 56u) {
            const short* sp = CinQ + ((size_t)(n * HW + irow * 56 + ix) * 256 + hh * 16);
            v8s q0 = *(const v8s*)sp;
            v8s q1 = *(const v8s*)(sp + 8);
            unsigned wq[4] = {0, 0, 0, 0};
            #pragma unroll
            for (int j = 0; j < 16; ++j) {
                short sv = j < 8 ? q0[j] : q1[j - 8];
                float y1 = fmaf((float)sv, a1s[hh][j], b1s[hh][j]);
                y1 = fminf(fmaxf(y1, 0.f), 1.f);
                wq[j >> 2] |= (unsigned)(unsigned char)(int)rintf(y1 * 15.f) << (8 * (j & 3));
            }
            v = (v4i){(int)wq[0], (int)wq[1], (int)wq[2], (int)wq[3]};
        }
        actT[hh * 233 + rr * 58 + px] = v;
    }
    __syncthreads();   // actT read-only from here

    int c0 = wave, c1 = wave + 4;
    const char* wgb = (const char*)Wp;
    stageW(wgb, (char*)&wbuf[0][0], 0, c0, c1, lane);

    int pidx[4];
    #pragma unroll
    for (int m = 0; m < 4; ++m) {
        int s = m * 32 + l31;
        int rr = s >> 6, col = s & 63;
        int xx = col < 56 ? col : 55;
        pidx[m] = (rr + 1) * 58 + xx + 1;
    }

    v16i acc[8] = {};

    int kt = 0;
    #pragma unroll 1
    for (int dyi = 0; dyi < 3; ++dyi) {
        #pragma unroll
        for (int dxi = 0; dxi < 3; ++dxi) {
            int doff = dyi * 58 + dxi - 59;
            #pragma unroll
            for (int kk = 0; kk < 8; ++kk) {
                int ktn = kt + 1; if (ktn > 71) ktn = 71;
                stageW(wgb, (char*)&wbuf[ktn & 1][0], ktn, c0, c1, lane);
                asm volatile("s_waitcnt vmcnt(2)" ::: "memory");
                const v4i* wb = &wbuf[kt & 1][0];
                int hb = (kk * 2 + half) * 233 + doff;
                v4i wf0 = wb[c0 * 64 + lane];
                v4i wf1 = wb[c1 * 64 + lane];
                v4i af0 = actT[hb + pidx[0]];
                v4i af1 = actT[hb + pidx[1]];
                v4i af2 = actT[hb + pidx[2]];
                v4i af3 = actT[hb + pidx[3]];
                acc[0] = __builtin_amdgcn_mfma_i32_32x32x32_i8(wf0, af0, acc[0], 0, 0, 0);
                acc[1] = __builtin_amdgcn_mfma_i32_32x32x32_i8(wf0, af1, acc[1], 0, 0, 0);
                acc[2] = __builtin_amdgcn_mfma_i32_32x32x32_i8(wf0, af2, acc[2], 0, 0, 0);
                acc[3] = __builtin_amdgcn_mfma_i32_32x32x32_i8(wf0, af3, acc[3], 0, 0, 0);
                acc[4] = __builtin_amdgcn_mfma_i32_32x32x32_i8(wf1, af0, acc[4], 0, 0, 0);
                acc[5] = __builtin_amdgcn_mfma_i32_32x32x32_i8(wf1, af1, acc[5], 0, 0, 0);
                acc[6] = __builtin_amdgcn_mfma_i32_32x32x32_i8(wf1, af2, acc[6], 0, 0, 0);
                acc[7] = __builtin_amdgcn_mfma_i32_32x32x32_i8(wf1, af3, acc[7], 0, 0, 0);
                ++kt;
            }
        }
    }
    asm volatile("s_waitcnt vmcnt(0)" ::: "memory");

    #pragma unroll
    for (int m = 0; m < 4; ++m) {
        int s = m * 32 + l31;
        int rr = s >> 6, col = s & 63;
        if (col < 56) {
            size_t boff = (size_t)n * NCH * HW + (size_t)(y0 + rr) * 56 + col;
            #pragma unroll
            for (int ci = 0; ci < 2; ++ci) {
                v16i a = acc[ci * 4 + m];
                #pragma unroll
                for (int r = 0; r < 16; ++r) {
                    int prow = (r & 3) + ((r >> 2) << 3) + (half << 2);
                    int co = (wave + ci * 4) * 32 + prow;
                    size_t off = boff + (size_t)co * HW;
                    Out[off] = fmaf(s1, (float)a[r], Xin[off]);
                }
            }
        }
    }
}

// conv1 fallback: reads pre-quantized padded acts (used when ws too small)
__global__ __launch_bounds__(256, 2) void conv1_plain(const int8_t* __restrict__ A,
        const v4i* __restrict__ Wp, const float* __restrict__ scales,
        const float* __restrict__ Xin, float* __restrict__ Out) {
    __shared__ v4i actT[16 * 233];
    __shared__ v4i wbuf[2][512];
    int tid = threadIdx.x;
    int lane = tid & 63, wave = tid >> 6;
    int rp = blockIdx.x, n = blockIdx.y;
    int y0 = rp * 2;
    int l31 = lane & 31, half = lane >> 5;

    float s1 = scales[1];

    const int8_t* asrc = A + (((size_t)n * PADH + y0) * PADH) * 256;
    for (int i = tid; i < 4 * 58 * 16; i += 256) {
        int rr = i / (58 * 16);
        int rem = i - rr * (58 * 16);
        int px = rem >> 4, hh = rem & 15;
        v4i v = *(const v4i*)(asrc + ((size_t)rr * PADH + px) * 256 + hh * 16);
        actT[hh * 233 + rr * 58 + px] = v;
    }
    __syncthreads();

    int c0 = wave, c1 = wave + 4;
    const char* wgb = (const char*)Wp;
    stageW(wgb, (char*)&wbuf[0][0], 0, c0, c1, lane);

    int pidx[4];
    #pragma unroll
    for (int m = 0; m < 4; ++m) {
        int s = m * 32 + l31;
        int rr = s >> 6, col = s & 63;
        int xx = col < 56 ? col : 55;
        pidx[m] = (rr + 1) * 58 + xx + 1;
    }

    v16i acc[8] = {};

    int kt = 0;
    #pragma unroll 1
    for (int dyi = 0; dyi < 3; ++dyi) {
        #pragma unroll
        for (int dxi = 0; dxi < 3; ++dxi) {
            int doff = dyi * 58 + dxi - 59;
            #pragma unroll
            for (int kk = 0; kk < 8; ++kk) {
                int ktn = kt + 1; if (ktn > 71) ktn = 71;
                stageW(wgb, (char*)&wbuf[ktn & 1][0], ktn, c0, c1, lane);
                asm volatile("s_waitcnt vmcnt(2)" ::: "memory");
                const v4i* wb = &wbuf[kt & 1][0];
                int hb = (kk * 2 + half) * 233 + doff;
                v4i wf0 = wb[c0 * 64 + lane];
                v4i wf1 = wb[c1 * 64 + lane];
                v4i af0 = actT[hb + pidx[0]];
                v4i af1 = actT[hb + pidx[1]];
                v4i af2 = actT[hb + pidx[2]];
                v4i af3 = actT[hb + pidx[3]];
                acc[0] = __builtin_amdgcn_mfma_i32_32x32x32_i8(wf0, af0, acc[0], 0, 0, 0);
                acc[1] = __builtin_amdgcn_mfma_i32_32x32x32_i8(wf0, af1, acc[1], 0, 0, 0);
                acc[2] = __builtin_amdgcn_mfma_i32_32x32x32_i8(wf0, af2, acc[2], 0, 0, 0);
                acc[3] = __builtin_amdgcn_mfma_i32_32x32x32_i8(wf0, af3, acc[3], 0, 0, 0);
                acc[4] = __builtin_amdgcn_mfma_i32_32x32x32_i8(wf1, af0, acc[4], 0, 0, 0);
                acc[5] = __builtin_amdgcn_mfma_i32_32x32x32_i8(wf1, af1, acc[5], 0, 0, 0);
                acc[6] = __builtin_amdgcn_mfma_i32_32x32x32_i8(wf1, af2, acc[6], 0, 0, 0);
                acc[7] = __builtin_amdgcn_mfma_i32_32x32x32_i8(wf1, af3, acc[7], 0, 0, 0);
                ++kt;
            }
        }
    }
    asm volatile("s_waitcnt vmcnt(0)" ::: "memory");

    #pragma unroll
    for (int m = 0; m < 4; ++m) {
        int s = m * 32 + l31;
        int rr = s >> 6, col = s & 63;
        if (col < 56) {
            size_t boff = (size_t)n * NCH * HW + (size_t)(y0 + rr) * 56 + col;
            #pragma unroll
            for (int ci = 0; ci < 2; ++ci) {
                v16i a = acc[ci * 4 + m];
                #pragma unroll
                for (int r = 0; r < 16; ++r) {
                    int prow = (r & 3) + ((r >> 2) << 3) + (half << 2);
                    int co = (wave + ci * 4) * 32 + prow;
                    size_t off = boff + (size_t)co * HW;
                    Out[off] = fmaf(s1, (float)a[r], Xin[off]);
                }
            }
        }
    }
}

// fallback only: requantize conv0 int16 output -> padded NHWC int8
__global__ __launch_bounds__(256) void quant1(const short* __restrict__ Cin,
        const unsigned long long* __restrict__ sums, const float* __restrict__ g,
        const float* __restrict__ bb, const float* __restrict__ scales,
        int8_t* __restrict__ A) {
    __shared__ float a1s[256], b1s[256];
    int t = threadIdx.x;
    {
        double sc0 = (double)scales[0];
        double S  = (double)(long long)sums[t];
        double S2 = (double)(long long)sums[256 + t];
        double meanS = S / (double)NPIX;
        double varS  = S2 / (double)NPIX - meanS * meanS;
        float meanf = (float)(sc0 * meanS);
        float varf  = (float)(sc0 * sc0 * varS);
        float rstd = (float)(1.0 / sqrt((double)varf + 1e-5));
        float gc = g[t], bc = bb[t];
        a1s[t] = (float)(sc0 * (double)rstd * (double)gc * 16.0);
        b1s[t] = bc - meanf * rstd * gc;
    }
    __syncthreads();
    for (int idx = blockIdx.x * 256 + t; idx < NPIX * 32; idx += gridDim.x * 256) {
        int e8 = idx * 8;
        int p = e8 >> 8, c8 = e8 & 255;
        int n = p / HW, r2 = p % HW, y = r2 / 56, xx = r2 % 56;
        v8s v = *(const v8s*)(Cin + e8);
        unsigned long long w = 0;
        #pragma unroll
        for (int j = 0; j < 8; ++j) {
            float y1 = fmaf((float)v[j], a1s[c8 + j], b1s[c8 + j]);
            y1 = fminf(fmaxf(y1, 0.f), 1.f);
            w |= (unsigned long long)(unsigned char)(int)rintf(y1 * 15.f) << (8 * j);
        }
        size_t dst = (((size_t)n * PADH + y + 1) * PADH + xx + 1) * 256 + c8;
        *(unsigned long long*)(A + dst) = w;
    }
}

extern "C" void kernel_launch(void* const* d_in, const int* in_sizes, int n_in,
                              void* d_out, int out_size, void* d_ws, size_t ws_size,
                              hipStream_t stream) {
    const float* x  = (const float*)d_in[0];
    const float* g0 = (const float*)d_in[1];
    const float* b0 = (const float*)d_in[2];
    const float* w0 = (const float*)d_in[3];
    const float* g1 = (const float*)d_in[4];
    const float* b1 = (const float*)d_in[5];
    const float* w1 = (const float*)d_in[6];
    float* out = (float*)d_out;

    char* ws = (char*)d_ws;
    int8_t* a0 = (int8_t*)(ws + A0_OFF);
    v4i* wp0 = (v4i*)(ws + WP0_OFF);
    v4i* wp1 = (v4i*)(ws + WP1_OFF);
    float* coef = (float*)(ws + COEF_OFF);
    float* A0c = coef;       float* B0c = coef + 256;
    float* scales = coef + 512;              // [0]=scale0 [1]=scale1
    unsigned* maxw = (unsigned*)(ws + MAXW_OFF);
    unsigned long long* sums = (unsigned long long*)(ws + SUM1_OFF);
    double2* part = (double2*)(ws + PART_OFF);

    // fused path (quant1 eliminated) if workspace can hold int16 Cout;
    // ws_size is fixed per-harness -> branch is deterministic & capture-safe.
    bool fuse = ws_size >= (size_t)CQ_OFF + CQ_BYTES;
    short* c0 = fuse ? (short*)(ws + CQ_OFF) : (short*)d_out;

    hipMemsetAsync(ws + MAXW_OFF, 0, 32 + 4096, stream);   // maxw + sums
    aux1<<<4608, 256, 0, stream>>>(x, part, w0, w1, maxw);
    aux2<<<257, 256, 0, stream>>>(part, g0, b0, w0, w1, maxw,
                                  A0c, B0c, (int8_t*)wp0, (int8_t*)wp1, scales);
    quant0<<<dim3(56, 16), 256, 0, stream>>>(x, A0c, B0c, a0);
    conv0_mfma<<<dim3(28, 16), 256, 0, stream>>>(a0, wp0, c0, sums);
    if (fuse) {
        conv1_fused<<<dim3(28, 16), 256, 0, stream>>>(c0, wp1, sums, g1, b1,
                                                      scales, x, out);
    } else {
        quant1<<<448, 256, 0, stream>>>(c0, sums, g1, b1, scales, a0);
        conv1_plain<<<dim3(28, 16), 256, 0, stream>>>(a0, wp1, scales, x, out);
    }
}

// Round 24
// 169.724 us; speedup vs baseline: 1.0029x; 1.0029x over previous
//
#include <hip/hip_runtime.h>
#include <stdint.h>
#include <math.h>

typedef int v4i  __attribute__((ext_vector_type(4)));
typedef int v16i __attribute__((ext_vector_type(16)));
typedef short v8s __attribute__((ext_vector_type(8)));

#define NIMG 16
#define NCH  256
#define HW   3136          // 56*56
#define NPIX 50176         // 16*3136
#define PADH 58
#define NKT  72            // 2304/32
#define NCOT 8             // 256/32
#define WELEMS 589824      // 256*256*3*3

// workspace layout (bytes)
#define A0_OFF   0
#define A0_BYTES (16*58*58*256)          // 13,778,944 padded NHWC int8 acts
#define WP0_OFF  (A0_OFF + A0_BYTES)
#define WP_BYTES (NKT*NCOT*64*16)        // 589,824 packed weight frags
#define WP1_OFF  (WP0_OFF + WP_BYTES)
#define COEF_OFF (WP1_OFF + WP_BYTES)    // floats A0[256] B0[256] scales[2]
#define MAXW_OFF (COEF_OFF + 4352)       // 2 x u32   (zeroed by 4KB memset)
#define SUM1_OFF (MAXW_OFF + 32)         // 512 x u64 (zeroed by 4KB memset)
#define PART_OFF (SUM1_OFF + 4096)       // 4096 x double2 (bn0 per-plane partials)
#define CQ_OFF   15032832                // 256-aligned; optional int16 Cout here
#define CQ_BYTES ((size_t)NPIX*256*2)    // 25,690,112

// aux1: blocks 0..4095 = bn0 per-plane partial sums; blocks 4096..4607 = wmax
__global__ __launch_bounds__(256) void aux1(const float* __restrict__ X,
        double2* __restrict__ part, const float* __restrict__ W0,
        const float* __restrict__ W1, unsigned* __restrict__ maxw) {
    int b = blockIdx.x;
    int tid = threadIdx.x;
    if (b < 4096) {
        const float4* src = (const float4*)(X + (size_t)b * HW);
        double s = 0.0, s2 = 0.0;
        for (int i = tid; i < HW / 4; i += 256) {
            float4 v = src[i];
            s  += (double)v.x + (double)v.y + (double)v.z + (double)v.w;
            s2 += (double)v.x * (double)v.x + (double)v.y * (double)v.y
                + (double)v.z * (double)v.z + (double)v.w * (double)v.w;
        }
        #pragma unroll
        for (int off = 32; off; off >>= 1) {
            s  += __shfl_xor(s, off);
            s2 += __shfl_xor(s2, off);
        }
        __shared__ double sh[8];
        int wave = tid >> 6, lane = tid & 63;
        if (lane == 0) { sh[wave * 2] = s; sh[wave * 2 + 1] = s2; }
        __syncthreads();
        if (tid == 0) {
            double2 o; o.x = sh[0] + sh[2] + sh[4] + sh[6];
            o.y = sh[1] + sh[3] + sh[5] + sh[7];
            part[b] = o;
        }
    } else {
        int wb = b - 4096;                 // 0..511
        int ten = wb >> 8, blk = wb & 255;
        const float* Wt = ten ? W1 : W0;
        __shared__ float sh[256];
        float m = 0.f;
        for (int i = blk * 256 + tid; i < WELEMS; i += 256 * 256)
            m = fmaxf(m, fabsf(Wt[i]));
        sh[tid] = m; __syncthreads();
        for (int o = 128; o > 0; o >>= 1) {
            if (tid < o) sh[tid] = fmaxf(sh[tid], sh[tid + o]);
            __syncthreads();
        }
        if (tid == 0) atomicMax(&maxw[ten], __float_as_uint(sh[0]));
    }
}

// aux2: block 0 = bn0 finalize; blocks 1..256 = weight quant+pack (TAP-MAJOR,
// matching the conv: k = tap*256 + ci; Wpack[kt][cot][lane][16])
__global__ __launch_bounds__(256) void aux2(const double2* __restrict__ part,
        const float* __restrict__ g, const float* __restrict__ bb,
        const float* __restrict__ W0, const float* __restrict__ W1,
        const unsigned* __restrict__ maxwBits, float* __restrict__ A0,
        float* __restrict__ B0, int8_t* __restrict__ D0, int8_t* __restrict__ D1,
        float* __restrict__ scales) {
    int b = blockIdx.x;
    int tid = threadIdx.x;
    if (b == 0) {
        int c = tid;
        double s = 0.0, s2 = 0.0;
        for (int n = 0; n < NIMG; ++n) {
            double2 v = part[n * 256 + c];
            s += v.x; s2 += v.y;
        }
        double mean = s / (double)NPIX;
        double var  = s2 / (double)NPIX - mean * mean;
        float meanf = (float)mean, varf = (float)var;
        float rstd = (float)(1.0 / sqrt((double)varf + 1e-5));
        float gc = g[c], bc = bb[c];
        A0[c] = rstd * gc;
        B0[c] = bc - meanf * rstd * gc;
    } else {
        int wb = b - 1;                    // 0..255
        int ten = wb >> 7, blk = wb & 127;
        const float* Wt = ten ? W1 : W0;
        int8_t* dst = ten ? D1 : D0;
        float maxw = tanhf(__uint_as_float(maxwBits[ten]));
        if (blk == 0 && tid == 0) scales[ten] = maxw / 225.f;
        float twoM = 2.f * maxw;
        for (int e = blk * 256 + tid; e < WELEMS; e += 128 * 256) {
            int o = e / 2304, rem = e % 2304;
            int ci = rem / 9, tap = rem % 9;
            float t = tanhf(Wt[e]);
            float wn = t / twoM + 0.5f;
            int r = (int)rintf(wn * 15.f);
            int q = 2 * r - 15;
            int k = tap * 256 + ci;        // tap-major conv layout
            int kt = k >> 5, k5 = k & 31;
            int lane = ((k5 >> 4) << 5) | (o & 31);
            int j = k5 & 15;
            dst[((((size_t)kt * NCOT + (o >> 5)) * 64 + lane) << 4) | j] = (int8_t)q;
        }
    }
}

// quantize BN0(x) -> padded NHWC int8 via LDS transpose; one block per (n,h).
// Also writes the pad halo zeros (replaces the 13.8MB memset).
__global__ __launch_bounds__(256) void quant0(const float* __restrict__ X,
        const float* __restrict__ A0, const float* __restrict__ B0,
        int8_t* __restrict__ Apad) {
    __shared__ int8_t tile[56 * 260];     // stride 260: conflict-free byte columns
    int h = blockIdx.x, n = blockIdx.y;
    int tid = threadIdx.x;
    const float4* src4 = (const float4*)X;
    for (int i = tid; i < 256 * 14; i += 256) {
        int c = i / 14, q = i - c * 14;
        float4 v = src4[((size_t)(n * 256 + c) * HW + h * 56) / 4 + q];
        float ac = A0[c], bc = B0[c];
        float vv[4] = {v.x, v.y, v.z, v.w};
        #pragma unroll
        for (int j = 0; j < 4; ++j) {
            float y = fmaf(vv[j], ac, bc);
            y = fminf(fmaxf(y, 0.f), 1.f);
            tile[(q * 4 + j) * 260 + c] = (int8_t)(int)rintf(y * 15.f);
        }
    }
    // halo zeroing (independent of tile)
    if (h == 0) {
        unsigned* r0  = (unsigned*)(Apad + ((size_t)n * PADH + 0) * PADH * 256);
        unsigned* r57 = (unsigned*)(Apad + (((size_t)n * PADH + 57) * PADH) * 256);
        for (int i = tid; i < 58 * 64; i += 256) { r0[i] = 0u; r57[i] = 0u; }
    }
    {
        unsigned* c0p  = (unsigned*)(Apad + (((size_t)n * PADH + h + 1) * PADH + 0) * 256);
        unsigned* c57p = (unsigned*)(Apad + (((size_t)n * PADH + h + 1) * PADH + 57) * 256);
        if (tid < 64) c0p[tid] = 0u;
        else if (tid < 128) c57p[tid - 64] = 0u;
    }
    __syncthreads();
    unsigned* dst = (unsigned*)(Apad + (((size_t)n * PADH + h + 1) * PADH + 1) * 256);
    for (int i = tid; i < 56 * 64; i += 256) {
        int w = i >> 6, c4 = (i & 63) << 2;
        dst[w * 64 + (c4 >> 2)] = *(const unsigned*)&tile[w * 260 + c4];
    }
}

typedef __attribute__((address_space(1))) const unsigned int gu32;
typedef __attribute__((address_space(3))) unsigned int lu32;
__device__ __forceinline__ void gll16(const void* g, void* l) {
    __builtin_amdgcn_global_load_lds((gu32*)g, (lu32*)l, 16, 0, 0);
}

// wave w stages its own two 1KB weight chunks (cout-tiles c0, c1) of K-step ktn
__device__ __forceinline__ void stageW(const char* wgb, char* ldsbuf,
        int ktn, int c0, int c1, int lane) {
    const char* src = wgb + (size_t)ktn * 8192;
    gll16(src + c0 * 1024 + lane * 16, ldsbuf + c0 * 1024 + lane * 16);
    gll16(src + c1 * 1024 + lane * 16, ldsbuf + c1 * 1024 + lane * 16);
}

// conv0: standalone (no template coupling). Block: 4 waves, 2 image rows x
// 256 couts; barrier-free K-loop, per-wave weight chunk ownership, vmcnt(2).
// Epilogue: int16 Cout ((s+8)>>4) + fused exact int64 bn1 stats.
__global__ __launch_bounds__(256, 2) void conv0_mfma(const int8_t* __restrict__ A,
        const v4i* __restrict__ Wp, short* __restrict__ Cout,
        unsigned long long* __restrict__ sums) {
    __shared__ v4i actT[16 * 233];        // 59.6 KB, read-only after prologue
    __shared__ v4i wbuf[2][512];          // 2 x 8 KB, per-wave chunk ownership
    int tid = threadIdx.x;
    int lane = tid & 63, wave = tid >> 6;
    int rp = blockIdx.x, n = blockIdx.y;
    int y0 = rp * 2;
    int l31 = lane & 31, half = lane >> 5;

    const int8_t* asrc = A + (((size_t)n * PADH + y0) * PADH) * 256;
    for (int i = tid; i < 4 * 58 * 16; i += 256) {
        int rr = i / (58 * 16);
        int rem = i - rr * (58 * 16);
        int px = rem >> 4, hh = rem & 15;
        v4i v = *(const v4i*)(asrc + ((size_t)rr * PADH + px) * 256 + hh * 16);
        actT[hh * 233 + rr * 58 + px] = v;
    }
    __syncthreads();   // actT read-only from here

    int c0 = wave, c1 = wave + 4;
    const char* wgb = (const char*)Wp;
    stageW(wgb, (char*)&wbuf[0][0], 0, c0, c1, lane);   // W[0], own chunks

    int pidx[4];
    #pragma unroll
    for (int m = 0; m < 4; ++m) {
        int s = m * 32 + l31;
        int rr = s >> 6, col = s & 63;
        int xx = col < 56 ? col : 55;
        pidx[m] = (rr + 1) * 58 + xx + 1;
    }

    v16i acc[8] = {};

    int kt = 0;
    #pragma unroll 1
    for (int dyi = 0; dyi < 3; ++dyi) {
        #pragma unroll
        for (int dxi = 0; dxi < 3; ++dxi) {
            int doff = dyi * 58 + dxi - 59;
            #pragma unroll
            for (int kk = 0; kk < 8; ++kk) {
                int ktn = kt + 1; if (ktn > 71) ktn = 71;
                stageW(wgb, (char*)&wbuf[ktn & 1][0], ktn, c0, c1, lane);
                asm volatile("s_waitcnt vmcnt(2)" ::: "memory");
                const v4i* wb = &wbuf[kt & 1][0];
                int hb = (kk * 2 + half) * 233 + doff;
                v4i wf0 = wb[c0 * 64 + lane];
                v4i wf1 = wb[c1 * 64 + lane];
                v4i af0 = actT[hb + pidx[0]];
                v4i af1 = actT[hb + pidx[1]];
                v4i af2 = actT[hb + pidx[2]];
                v4i af3 = actT[hb + pidx[3]];
                acc[0] = __builtin_amdgcn_mfma_i32_32x32x32_i8(af0, wf0, acc[0], 0, 0, 0);
                acc[1] = __builtin_amdgcn_mfma_i32_32x32x32_i8(af1, wf0, acc[1], 0, 0, 0);
                acc[2] = __builtin_amdgcn_mfma_i32_32x32x32_i8(af2, wf0, acc[2], 0, 0, 0);
                acc[3] = __builtin_amdgcn_mfma_i32_32x32x32_i8(af3, wf0, acc[3], 0, 0, 0);
                acc[4] = __builtin_amdgcn_mfma_i32_32x32x32_i8(af0, wf1, acc[4], 0, 0, 0);
                acc[5] = __builtin_amdgcn_mfma_i32_32x32x32_i8(af1, wf1, acc[5], 0, 0, 0);
                acc[6] = __builtin_amdgcn_mfma_i32_32x32x32_i8(af2, wf1, acc[6], 0, 0, 0);
                acc[7] = __builtin_amdgcn_mfma_i32_32x32x32_i8(af3, wf1, acc[7], 0, 0, 0);
                ++kt;
            }
        }
    }
    asm volatile("s_waitcnt vmcnt(0)" ::: "memory");

    int pbase = n * HW + y0 * 56;
    #pragma unroll
    for (int ci = 0; ci < 2; ++ci) {
        int co = (wave + ci * 4) * 32 + l31;
        long long ssum = 0, ssq = 0;
        #pragma unroll
        for (int m = 0; m < 4; ++m) {
            v16i a = acc[ci * 4 + m];
            #pragma unroll
            for (int r = 0; r < 16; ++r) {
                int prow = (r & 3) + ((r >> 2) << 3) + (half << 2);
                int s = m * 32 + prow;
                int rr = s >> 6, col = s & 63;
                if (col < 56) {
                    Cout[(size_t)(pbase + rr * 56 + col) * 256 + co] =
                        (short)((a[r] + 8) >> 4);
                    ssum += a[r];
                    ssq  += (long long)a[r] * a[r];
                }
            }
        }
        ssum += __shfl_xor(ssum, 32);
        ssq  += __shfl_xor(ssq, 32);
        if (half == 0) {
            atomicAdd(&sums[co], (unsigned long long)ssum);
            atomicAdd(&sums[256 + co], (unsigned long long)ssq);
        }
    }
}

// conv1 fused: reads int16 Cout directly, computes BN1 affine per block from
// exact sums, quantizes inline during act staging. Coeffs in padded [16][17]
// LDS (bank stride 17 -> staging reads conflict-free).
__global__ __launch_bounds__(256, 2) void conv1_fused(const short* __restrict__ CinQ,
        const v4i* __restrict__ Wp, const unsigned long long* __restrict__ sums,
        const float* __restrict__ g, const float* __restrict__ bb,
        const float* __restrict__ scales, const float* __restrict__ Xin,
        float* __restrict__ Out) {
    __shared__ v4i actT[16 * 233];
    __shared__ v4i wbuf[2][512];
    __shared__ float a1s[16][17], b1s[16][17];   // +1 pad: conflict-free
    int tid = threadIdx.x;
    int lane = tid & 63, wave = tid >> 6;
    int rp = blockIdx.x, n = blockIdx.y;
    int y0 = rp * 2;
    int l31 = lane & 31, half = lane >> 5;

    float s1 = scales[1];

    {   // per-block BN1 coeff compute from exact int64 sums
        int c = tid;
        double sc0 = (double)scales[0];
        double S  = (double)(long long)sums[c];
        double S2 = (double)(long long)sums[256 + c];
        double meanS = S / (double)NPIX;
        double varS  = S2 / (double)NPIX - meanS * meanS;
        float meanf = (float)(sc0 * meanS);
        float varf  = (float)(sc0 * sc0 * varS);
        float rstd = (float)(1.0 / sqrt((double)varf + 1e-5));
        float gc = g[c], bc = bb[c];
        a1s[c >> 4][c & 15] = (float)(sc0 * (double)rstd * (double)gc * 16.0);
        b1s[c >> 4][c & 15] = bc - meanf * rstd * gc;
    }
    __syncthreads();
    for (int i = tid; i < 4 * 58 * 16; i += 256) {
        int rr = i / (58 * 16);
        int rem = i - rr * (58 * 16);
        int px = rem >> 4, hh = rem & 15;
        int irow = y0 + rr - 1, ix = px - 1;
        v4i v = {0, 0, 0, 0};
        if ((unsigned)irow < 56u && (unsigned)ix < 56u) {
            const short* sp = CinQ + ((size_t)(n * HW + irow * 56 + ix) * 256 + hh * 16);
            v8s q0 = *(const v8s*)sp;
            v8s q1 = *(const v8s*)(sp + 8);
            unsigned wq[4] = {0, 0, 0, 0};
            #pragma unroll
            for (int j = 0; j < 16; ++j) {
                short sv = j < 8 ? q0[j] : q1[j - 8];
                float y1 = fmaf((float)sv, a1s[hh][j], b1s[hh][j]);
                y1 = fminf(fmaxf(y1, 0.f), 1.f);
                wq[j >> 2] |= (unsigned)(unsigned char)(int)rintf(y1 * 15.f) << (8 * (j & 3));
            }
            v = (v4i){(int)wq[0], (int)wq[1], (int)wq[2], (int)wq[3]};
        }
        actT[hh * 233 + rr * 58 + px] = v;
    }
    __syncthreads();   // actT read-only from here

    int c0 = wave, c1 = wave + 4;
    const char* wgb = (const char*)Wp;
    stageW(wgb, (char*)&wbuf[0][0], 0, c0, c1, lane);

    int pidx[4];
    #pragma unroll
    for (int m = 0; m < 4; ++m) {
        int s = m * 32 + l31;
        int rr = s >> 6, col = s & 63;
        int xx = col < 56 ? col : 55;
        pidx[m] = (rr + 1) * 58 + xx + 1;
    }

    v16i acc[8] = {};

    int kt = 0;
    #pragma unroll 1
    for (int dyi = 0; dyi < 3; ++dyi) {
        #pragma unroll
        for (int dxi = 0; dxi < 3; ++dxi) {
            int doff = dyi * 58 + dxi - 59;
            #pragma unroll
            for (int kk = 0; kk < 8; ++kk) {
                int ktn = kt + 1; if (ktn > 71) ktn = 71;
                stageW(wgb, (char*)&wbuf[ktn & 1][0], ktn, c0, c1, lane);
                asm volatile("s_waitcnt vmcnt(2)" ::: "memory");
                const v4i* wb = &wbuf[kt & 1][0];
                int hb = (kk * 2 + half) * 233 + doff;
                v4i wf0 = wb[c0 * 64 + lane];
                v4i wf1 = wb[c1 * 64 + lane];
                v4i af0 = actT[hb + pidx[0]];
                v4i af1 = actT[hb + pidx[1]];
                v4i af2 = actT[hb + pidx[2]];
                v4i af3 = actT[hb + pidx[3]];
                acc[0] = __builtin_amdgcn_mfma_i32_32x32x32_i8(wf0, af0, acc[0], 0, 0, 0);
                acc[1] = __builtin_amdgcn_mfma_i32_32x32x32_i8(wf0, af1, acc[1], 0, 0, 0);
                acc[2] = __builtin_amdgcn_mfma_i32_32x32x32_i8(wf0, af2, acc[2], 0, 0, 0);
                acc[3] = __builtin_amdgcn_mfma_i32_32x32x32_i8(wf0, af3, acc[3], 0, 0, 0);
                acc[4] = __builtin_amdgcn_mfma_i32_32x32x32_i8(wf1, af0, acc[4], 0, 0, 0);
                acc[5] = __builtin_amdgcn_mfma_i32_32x32x32_i8(wf1, af1, acc[5], 0, 0, 0);
                acc[6] = __builtin_amdgcn_mfma_i32_32x32x32_i8(wf1, af2, acc[6], 0, 0, 0);
                acc[7] = __builtin_amdgcn_mfma_i32_32x32x32_i8(wf1, af3, acc[7], 0, 0, 0);
                ++kt;
            }
        }
    }
    asm volatile("s_waitcnt vmcnt(0)" ::: "memory");

    #pragma unroll
    for (int m = 0; m < 4; ++m) {
        int s = m * 32 + l31;
        int rr = s >> 6, col = s & 63;
        if (col < 56) {
            size_t boff = (size_t)n * NCH * HW + (size_t)(y0 + rr) * 56 + col;
            #pragma unroll
            for (int ci = 0; ci < 2; ++ci) {
                v16i a = acc[ci * 4 + m];
                #pragma unroll
                for (int r = 0; r < 16; ++r) {
                    int prow = (r & 3) + ((r >> 2) << 3) + (half << 2);
                    int co = (wave + ci * 4) * 32 + prow;
                    size_t off = boff + (size_t)co * HW;
                    Out[off] = fmaf(s1, (float)a[r], Xin[off]);
                }
            }
        }
    }
}

// conv1 fallback: reads pre-quantized padded acts (used when ws too small)
__global__ __launch_bounds__(256, 2) void conv1_plain(const int8_t* __restrict__ A,
        const v4i* __restrict__ Wp, const float* __restrict__ scales,
        const float* __restrict__ Xin, float* __restrict__ Out) {
    __shared__ v4i actT[16 * 233];
    __shared__ v4i wbuf[2][512];
    int tid = threadIdx.x;
    int lane = tid & 63, wave = tid >> 6;
    int rp = blockIdx.x, n = blockIdx.y;
    int y0 = rp * 2;
    int l31 = lane & 31, half = lane >> 5;

    float s1 = scales[1];

    const int8_t* asrc = A + (((size_t)n * PADH + y0) * PADH) * 256;
    for (int i = tid; i < 4 * 58 * 16; i += 256) {
        int rr = i / (58 * 16);
        int rem = i - rr * (58 * 16);
        int px = rem >> 4, hh = rem & 15;
        v4i v = *(const v4i*)(asrc + ((size_t)rr * PADH + px) * 256 + hh * 16);
        actT[hh * 233 + rr * 58 + px] = v;
    }
    __syncthreads();

    int c0 = wave, c1 = wave + 4;
    const char* wgb = (const char*)Wp;
    stageW(wgb, (char*)&wbuf[0][0], 0, c0, c1, lane);

    int pidx[4];
    #pragma unroll
    for (int m = 0; m < 4; ++m) {
        int s = m * 32 + l31;
        int rr = s >> 6, col = s & 63;
        int xx = col < 56 ? col : 55;
        pidx[m] = (rr + 1) * 58 + xx + 1;
    }

    v16i acc[8] = {};

    int kt = 0;
    #pragma unroll 1
    for (int dyi = 0; dyi < 3; ++dyi) {
        #pragma unroll
        for (int dxi = 0; dxi < 3; ++dxi) {
            int doff = dyi * 58 + dxi - 59;
            #pragma unroll
            for (int kk = 0; kk < 8; ++kk) {
                int ktn = kt + 1; if (ktn > 71) ktn = 71;
                stageW(wgb, (char*)&wbuf[ktn & 1][0], ktn, c0, c1, lane);
                asm volatile("s_waitcnt vmcnt(2)" ::: "memory");
                const v4i* wb = &wbuf[kt & 1][0];
                int hb = (kk * 2 + half) * 233 + doff;
                v4i wf0 = wb[c0 * 64 + lane];
                v4i wf1 = wb[c1 * 64 + lane];
                v4i af0 = actT[hb + pidx[0]];
                v4i af1 = actT[hb + pidx[1]];
                v4i af2 = actT[hb + pidx[2]];
                v4i af3 = actT[hb + pidx[3]];
                acc[0] = __builtin_amdgcn_mfma_i32_32x32x32_i8(wf0, af0, acc[0], 0, 0, 0);
                acc[1] = __builtin_amdgcn_mfma_i32_32x32x32_i8(wf0, af1, acc[1], 0, 0, 0);
                acc[2] = __builtin_amdgcn_mfma_i32_32x32x32_i8(wf0, af2, acc[2], 0, 0, 0);
                acc[3] = __builtin_amdgcn_mfma_i32_32x32x32_i8(wf0, af3, acc[3], 0, 0, 0);
                acc[4] = __builtin_amdgcn_mfma_i32_32x32x32_i8(wf1, af0, acc[4], 0, 0, 0);
                acc[5] = __builtin_amdgcn_mfma_i32_32x32x32_i8(wf1, af1, acc[5], 0, 0, 0);
                acc[6] = __builtin_amdgcn_mfma_i32_32x32x32_i8(wf1, af2, acc[6], 0, 0, 0);
                acc[7] = __builtin_amdgcn_mfma_i32_32x32x32_i8(wf1, af3, acc[7], 0, 0, 0);
                ++kt;
            }
        }
    }
    asm volatile("s_waitcnt vmcnt(0)" ::: "memory");

    #pragma unroll
    for (int m = 0; m < 4; ++m) {
        int s = m * 32 + l31;
        int rr = s >> 6, col = s & 63;
        if (col < 56) {
            size_t boff = (size_t)n * NCH * HW + (size_t)(y0 + rr) * 56 + col;
            #pragma unroll
            for (int ci = 0; ci < 2; ++ci) {
                v16i a = acc[ci * 4 + m];
                #pragma unroll
                for (int r = 0; r < 16; ++r) {
                    int prow = (r & 3) + ((r >> 2) << 3) + (half << 2);
                    int co = (wave + ci * 4) * 32 + prow;
                    size_t off = boff + (size_t)co * HW;
                    Out[off] = fmaf(s1, (float)a[r], Xin[off]);
                }
            }
        }
    }
}

// fallback only: requantize conv0 int16 output -> padded NHWC int8
__global__ __launch_bounds__(256) void quant1(const short* __restrict__ Cin,
        const unsigned long long* __restrict__ sums, const float* __restrict__ g,
        const float* __restrict__ bb, const float* __restrict__ scales,
        int8_t* __restrict__ A) {
    __shared__ float a1s[256], b1s[256];
    int t = threadIdx.x;
    {
        double sc0 = (double)scales[0];
        double S  = (double)(long long)sums[t];
        double S2 = (double)(long long)sums[256 + t];
        double meanS = S / (double)NPIX;
        double varS  = S2 / (double)NPIX - meanS * meanS;
        float meanf = (float)(sc0 * meanS);
        float varf  = (float)(sc0 * sc0 * varS);
        float rstd = (float)(1.0 / sqrt((double)varf + 1e-5));
        float gc = g[t], bc = bb[t];
        a1s[t] = (float)(sc0 * (double)rstd * (double)gc * 16.0);
        b1s[t] = bc - meanf * rstd * gc;
    }
    __syncthreads();
    for (int idx = blockIdx.x * 256 + t; idx < NPIX * 32; idx += gridDim.x * 256) {
        int e8 = idx * 8;
        int p = e8 >> 8, c8 = e8 & 255;
        int n = p / HW, r2 = p % HW, y = r2 / 56, xx = r2 % 56;
        v8s v = *(const v8s*)(Cin + e8);
        unsigned long long w = 0;
        #pragma unroll
        for (int j = 0; j < 8; ++j) {
            float y1 = fmaf((float)v[j], a1s[c8 + j], b1s[c8 + j]);
            y1 = fminf(fmaxf(y1, 0.f), 1.f);
            w |= (unsigned long long)(unsigned char)(int)rintf(y1 * 15.f) << (8 * j);
        }
        size_t dst = (((size_t)n * PADH + y + 1) * PADH + xx + 1) * 256 + c8;
        *(unsigned long long*)(A + dst) = w;
    }
}

extern "C" void kernel_launch(void* const* d_in, const int* in_sizes, int n_in,
                              void* d_out, int out_size, void* d_ws, size_t ws_size,
                              hipStream_t stream) {
    const float* x  = (const float*)d_in[0];
    const float* g0 = (const float*)d_in[1];
    const float* b0 = (const float*)d_in[2];
    const float* w0 = (const float*)d_in[3];
    const float* g1 = (const float*)d_in[4];
    const float* b1 = (const float*)d_in[5];
    const float* w1 = (const float*)d_in[6];
    float* out = (float*)d_out;

    char* ws = (char*)d_ws;
    int8_t* a0 = (int8_t*)(ws + A0_OFF);
    v4i* wp0 = (v4i*)(ws + WP0_OFF);
    v4i* wp1 = (v4i*)(ws + WP1_OFF);
    float* coef = (float*)(ws + COEF_OFF);
    float* A0c = coef;       float* B0c = coef + 256;
    float* scales = coef + 512;              // [0]=scale0 [1]=scale1
    unsigned* maxw = (unsigned*)(ws + MAXW_OFF);
    unsigned long long* sums = (unsigned long long*)(ws + SUM1_OFF);
    double2* part = (double2*)(ws + PART_OFF);

    // fused path (quant1 eliminated) if workspace can hold int16 Cout;
    // ws_size is fixed per-harness -> branch is deterministic & capture-safe.
    bool fuse = ws_size >= (size_t)CQ_OFF + CQ_BYTES;
    short* c0 = fuse ? (short*)(ws + CQ_OFF) : (short*)d_out;

    hipMemsetAsync(ws + MAXW_OFF, 0, 32 + 4096, stream);   // maxw + sums
    aux1<<<4608, 256, 0, stream>>>(x, part, w0, w1, maxw);
    aux2<<<257, 256, 0, stream>>>(part, g0, b0, w0, w1, maxw,
                                  A0c, B0c, (int8_t*)wp0, (int8_t*)wp1, scales);
    quant0<<<dim3(56, 16), 256, 0, stream>>>(x, A0c, B0c, a0);
    conv0_mfma<<<dim3(28, 16), 256, 0, stream>>>(a0, wp0, c0, sums);
    if (fuse) {
        conv1_fused<<<dim3(28, 16), 256, 0, stream>>>(c0, wp1, sums, g1, b1,
                                                      scales, x, out);
    } else {
        quant1<<<448, 256, 0, stream>>>(c0, sums, g1, b1, scales, a0);
        conv1_plain<<<dim3(28, 16), 256, 0, stream>>>(a0, wp1, scales, x, out);
    }
}

// Round 25
// 169.531 us; speedup vs baseline: 1.0041x; 1.0011x over previous
//
#include <hip/hip_runtime.h>
#include <stdint.h>
#include <math.h>

typedef int v4i  __attribute__((ext_vector_type(4)));
typedef int v16i __attribute__((ext_vector_type(16)));
typedef short v8s __attribute__((ext_vector_type(8)));

#define NIMG 16
#define NCH  256
#define HW   3136          // 56*56
#define NPIX 50176         // 16*3136
#define PADH 58
#define NKT  72            // 2304/32
#define NCOT 8             // 256/32
#define WELEMS 589824      // 256*256*3*3

// workspace layout (bytes)
#define A0_OFF   0
#define A0_BYTES (16*58*58*256)          // 13,778,944 padded NHWC int8 acts
#define WP0_OFF  (A0_OFF + A0_BYTES)
#define WP_BYTES (NKT*NCOT*64*16)        // 589,824 packed weight frags
#define WP1_OFF  (WP0_OFF + WP_BYTES)
#define COEF_OFF (WP1_OFF + WP_BYTES)    // floats A0[256] B0[256] scales[2]
#define MAXW_OFF (COEF_OFF + 4352)       // 2 x u32   (zeroed by 4KB memset)
#define SUM1_OFF (MAXW_OFF + 32)         // 512 x u64 (zeroed by 4KB memset)
#define PART_OFF (SUM1_OFF + 4096)       // 4096 x double2 (bn0 per-plane partials)
#define CQ_OFF   15032832                // 256-aligned; optional int16 Cout here
#define CQ_BYTES ((size_t)NPIX*256*2)    // 25,690,112

// aux1: blocks 0..4095 = bn0 per-plane partial sums; blocks 4096..4607 = wmax
__global__ __launch_bounds__(256) void aux1(const float* __restrict__ X,
        double2* __restrict__ part, const float* __restrict__ W0,
        const float* __restrict__ W1, unsigned* __restrict__ maxw) {
    int b = blockIdx.x;
    int tid = threadIdx.x;
    if (b < 4096) {
        const float4* src = (const float4*)(X + (size_t)b * HW);
        double s = 0.0, s2 = 0.0;
        for (int i = tid; i < HW / 4; i += 256) {
            float4 v = src[i];
            s  += (double)v.x + (double)v.y + (double)v.z + (double)v.w;
            s2 += (double)v.x * (double)v.x + (double)v.y * (double)v.y
                + (double)v.z * (double)v.z + (double)v.w * (double)v.w;
        }
        #pragma unroll
        for (int off = 32; off; off >>= 1) {
            s  += __shfl_xor(s, off);
            s2 += __shfl_xor(s2, off);
        }
        __shared__ double sh[8];
        int wave = tid >> 6, lane = tid & 63;
        if (lane == 0) { sh[wave * 2] = s; sh[wave * 2 + 1] = s2; }
        __syncthreads();
        if (tid == 0) {
            double2 o; o.x = sh[0] + sh[2] + sh[4] + sh[6];
            o.y = sh[1] + sh[3] + sh[5] + sh[7];
            part[b] = o;
        }
    } else {
        int wb = b - 4096;                 // 0..511
        int ten = wb >> 8, blk = wb & 255;
        const float* Wt = ten ? W1 : W0;
        __shared__ float sh[256];
        float m = 0.f;
        for (int i = blk * 256 + tid; i < WELEMS; i += 256 * 256)
            m = fmaxf(m, fabsf(Wt[i]));
        sh[tid] = m; __syncthreads();
        for (int o = 128; o > 0; o >>= 1) {
            if (tid < o) sh[tid] = fmaxf(sh[tid], sh[tid + o]);
            __syncthreads();
        }
        if (tid == 0) atomicMax(&maxw[ten], __float_as_uint(sh[0]));
    }
}

// aux2: block 0 = bn0 finalize; blocks 1..256 = weight quant+pack (TAP-MAJOR,
// matching the conv: k = tap*256 + ci; Wpack[kt][cot][lane][16])
__global__ __launch_bounds__(256) void aux2(const double2* __restrict__ part,
        const float* __restrict__ g, const float* __restrict__ bb,
        const float* __restrict__ W0, const float* __restrict__ W1,
        const unsigned* __restrict__ maxwBits, float* __restrict__ A0,
        float* __restrict__ B0, int8_t* __restrict__ D0, int8_t* __restrict__ D1,
        float* __restrict__ scales) {
    int b = blockIdx.x;
    int tid = threadIdx.x;
    if (b == 0) {
        int c = tid;
        double s = 0.0, s2 = 0.0;
        for (int n = 0; n < NIMG; ++n) {
            double2 v = part[n * 256 + c];
            s += v.x; s2 += v.y;
        }
        double mean = s / (double)NPIX;
        double var  = s2 / (double)NPIX - mean * mean;
        float meanf = (float)mean, varf = (float)var;
        float rstd = (float)(1.0 / sqrt((double)varf + 1e-5));
        float gc = g[c], bc = bb[c];
        A0[c] = rstd * gc;
        B0[c] = bc - meanf * rstd * gc;
    } else {
        int wb = b - 1;                    // 0..255
        int ten = wb >> 7, blk = wb & 127;
        const float* Wt = ten ? W1 : W0;
        int8_t* dst = ten ? D1 : D0;
        float maxw = tanhf(__uint_as_float(maxwBits[ten]));
        if (blk == 0 && tid == 0) scales[ten] = maxw / 225.f;
        float twoM = 2.f * maxw;
        for (int e = blk * 256 + tid; e < WELEMS; e += 128 * 256) {
            int o = e / 2304, rem = e % 2304;
            int ci = rem / 9, tap = rem % 9;
            float t = tanhf(Wt[e]);
            float wn = t / twoM + 0.5f;
            int r = (int)rintf(wn * 15.f);
            int q = 2 * r - 15;
            int k = tap * 256 + ci;        // tap-major conv layout
            int kt = k >> 5, k5 = k & 31;
            int lane = ((k5 >> 4) << 5) | (o & 31);
            int j = k5 & 15;
            dst[((((size_t)kt * NCOT + (o >> 5)) * 64 + lane) << 4) | j] = (int8_t)q;
        }
    }
}

// quantize BN0(x) -> padded NHWC int8 via LDS transpose; one block per (n,h).
// Also writes the pad halo zeros (replaces the 13.8MB memset).
__global__ __launch_bounds__(256) void quant0(const float* __restrict__ X,
        const float* __restrict__ A0, const float* __restrict__ B0,
        int8_t* __restrict__ Apad) {
    __shared__ int8_t tile[56 * 260];     // stride 260: conflict-free byte columns
    int h = blockIdx.x, n = blockIdx.y;
    int tid = threadIdx.x;
    const float4* src4 = (const float4*)X;
    for (int i = tid; i < 256 * 14; i += 256) {
        int c = i / 14, q = i - c * 14;
        float4 v = src4[((size_t)(n * 256 + c) * HW + h * 56) / 4 + q];
        float ac = A0[c], bc = B0[c];
        float vv[4] = {v.x, v.y, v.z, v.w};
        #pragma unroll
        for (int j = 0; j < 4; ++j) {
            float y = fmaf(vv[j], ac, bc);
            y = fminf(fmaxf(y, 0.f), 1.f);
            tile[(q * 4 + j) * 260 + c] = (int8_t)(int)rintf(y * 15.f);
        }
    }
    // halo zeroing (independent of tile)
    if (h == 0) {
        unsigned* r0  = (unsigned*)(Apad + ((size_t)n * PADH + 0) * PADH * 256);
        unsigned* r57 = (unsigned*)(Apad + (((size_t)n * PADH + 57) * PADH) * 256);
        for (int i = tid; i < 58 * 64; i += 256) { r0[i] = 0u; r57[i] = 0u; }
    }
    {
        unsigned* c0p  = (unsigned*)(Apad + (((size_t)n * PADH + h + 1) * PADH + 0) * 256);
        unsigned* c57p = (unsigned*)(Apad + (((size_t)n * PADH + h + 1) * PADH + 57) * 256);
        if (tid < 64) c0p[tid] = 0u;
        else if (tid < 128) c57p[tid - 64] = 0u;
    }
    __syncthreads();
    unsigned* dst = (unsigned*)(Apad + (((size_t)n * PADH + h + 1) * PADH + 1) * 256);
    for (int i = tid; i < 56 * 64; i += 256) {
        int w = i >> 6, c4 = (i & 63) << 2;
        dst[w * 64 + (c4 >> 2)] = *(const unsigned*)&tile[w * 260 + c4];
    }
}

typedef __attribute__((address_space(1))) const unsigned int gu32;
typedef __attribute__((address_space(3))) unsigned int lu32;
__device__ __forceinline__ void gll16(const void* g, void* l) {
    __builtin_amdgcn_global_load_lds((gu32*)g, (lu32*)l, 16, 0, 0);
}

// wave w stages its own two 1KB weight chunks (cout-tiles c0, c1) of K-step ktn
__device__ __forceinline__ void stageW(const char* wgb, char* ldsbuf,
        int ktn, int c0, int c1, int lane) {
    const char* src = wgb + (size_t)ktn * 8192;
    gll16(src + c0 * 1024 + lane * 16, ldsbuf + c0 * 1024 + lane * 16);
    gll16(src + c1 * 1024 + lane * 16, ldsbuf + c1 * 1024 + lane * 16);
}

// conv0: standalone (no template coupling). Block: 4 waves, 2 image rows x
// 256 couts; barrier-free K-loop, per-wave weight chunk ownership, vmcnt(2).
// Epilogue: int16 Cout ((s+8)>>4) + fused exact int64 bn1 stats.
__global__ __launch_bounds__(256, 2) void conv0_mfma(const int8_t* __restrict__ A,
        const v4i* __restrict__ Wp, short* __restrict__ Cout,
        unsigned long long* __restrict__ sums) {
    __shared__ v4i actT[16 * 233];        // 59.6 KB, read-only after prologue
    __shared__ v4i wbuf[2][512];          // 2 x 8 KB, per-wave chunk ownership
    int tid = threadIdx.x;
    int lane = tid & 63, wave = tid >> 6;
    int rp = blockIdx.x, n = blockIdx.y;
    int y0 = rp * 2;
    int l31 = lane & 31, half = lane >> 5;

    const int8_t* asrc = A + (((size_t)n * PADH + y0) * PADH) * 256;
    for (int i = tid; i < 4 * 58 * 16; i += 256) {
        int rr = i / (58 * 16);
        int rem = i - rr * (58 * 16);
        int px = rem >> 4, hh = rem & 15;
        v4i v = *(const v4i*)(asrc + ((size_t)rr * PADH + px) * 256 + hh * 16);
        actT[hh * 233 + rr * 58 + px] = v;
    }
    __syncthreads();   // actT read-only from here

    int c0 = wave, c1 = wave + 4;
    const char* wgb = (const char*)Wp;
    stageW(wgb, (char*)&wbuf[0][0], 0, c0, c1, lane);   // W[0], own chunks

    int pidx[4];
    #pragma unroll
    for (int m = 0; m < 4; ++m) {
        int s = m * 32 + l31;
        int rr = s >> 6, col = s & 63;
        int xx = col < 56 ? col : 55;
        pidx[m] = (rr + 1) * 58 + xx + 1;
    }

    v16i acc[8] = {};

    int kt = 0;
    #pragma unroll 1
    for (int dyi = 0; dyi < 3; ++dyi) {
        #pragma unroll
        for (int dxi = 0; dxi < 3; ++dxi) {
            int doff = dyi * 58 + dxi - 59;
            #pragma unroll
            for (int kk = 0; kk < 8; ++kk) {
                int ktn = kt + 1; if (ktn > 71) ktn = 71;
                stageW(wgb, (char*)&wbuf[ktn & 1][0], ktn, c0, c1, lane);
                asm volatile("s_waitcnt vmcnt(2)" ::: "memory");
                const v4i* wb = &wbuf[kt & 1][0];
                int hb = (kk * 2 + half) * 233 + doff;
                v4i wf0 = wb[c0 * 64 + lane];
                v4i wf1 = wb[c1 * 64 + lane];
                v4i af0 = actT[hb + pidx[0]];
                v4i af1 = actT[hb + pidx[1]];
                v4i af2 = actT[hb + pidx[2]];
                v4i af3 = actT[hb + pidx[3]];
                acc[0] = __builtin_amdgcn_mfma_i32_32x32x32_i8(af0, wf0, acc[0], 0, 0, 0);
                acc[1] = __builtin_amdgcn_mfma_i32_32x32x32_i8(af1, wf0, acc[1], 0, 0, 0);
                acc[2] = __builtin_amdgcn_mfma_i32_32x32x32_i8(af2, wf0, acc[2], 0, 0, 0);
                acc[3] = __builtin_amdgcn_mfma_i32_32x32x32_i8(af3, wf0, acc[3], 0, 0, 0);
                acc[4] = __builtin_amdgcn_mfma_i32_32x32x32_i8(af0, wf1, acc[4], 0, 0, 0);
                acc[5] = __builtin_amdgcn_mfma_i32_32x32x32_i8(af1, wf1, acc[5], 0, 0, 0);
                acc[6] = __builtin_amdgcn_mfma_i32_32x32x32_i8(af2, wf1, acc[6], 0, 0, 0);
                acc[7] = __builtin_amdgcn_mfma_i32_32x32x32_i8(af3, wf1, acc[7], 0, 0, 0);
                ++kt;
            }
        }
    }
    asm volatile("s_waitcnt vmcnt(0)" ::: "memory");

    int pbase = n * HW + y0 * 56;
    #pragma unroll
    for (int ci = 0; ci < 2; ++ci) {
        int co = (wave + ci * 4) * 32 + l31;
        long long ssum = 0, ssq = 0;
        #pragma unroll
        for (int m = 0; m < 4; ++m) {
            v16i a = acc[ci * 4 + m];
            #pragma unroll
            for (int r = 0; r < 16; ++r) {
                int prow = (r & 3) + ((r >> 2) << 3) + (half << 2);
                int s = m * 32 + prow;
                int rr = s >> 6, col = s & 63;
                if (col < 56) {
                    Cout[(size_t)(pbase + rr * 56 + col) * 256 + co] =
                        (short)((a[r] + 8) >> 4);
                    ssum += a[r];
                    ssq  += (long long)a[r] * a[r];
                }
            }
        }
        ssum += __shfl_xor(ssum, 32);
        ssq  += __shfl_xor(ssq, 32);
        if (half == 0) {
            atomicAdd(&sums[co], (unsigned long long)ssum);
            atomicAdd(&sums[256 + co], (unsigned long long)ssq);
        }
    }
}

// conv1 fused: reads int16 Cout directly, computes BN1 affine per block from
// exact sums, quantizes inline during act staging. Coeffs in padded [16][17]
// LDS (bank stride 17 -> staging reads conflict-free).
__global__ __launch_bounds__(256, 2) void conv1_fused(const short* __restrict__ CinQ,
        const v4i* __restrict__ Wp, const unsigned long long* __restrict__ sums,
        const float* __restrict__ g, const float* __restrict__ bb,
        const float* __restrict__ scales, const float* __restrict__ Xin,
        float* __restrict__ Out) {
    __shared__ v4i actT[16 * 233];
    __shared__ v4i wbuf[2][512];
    __shared__ float a1s[16][17], b1s[16][17];   // +1 pad: conflict-free
    int tid = threadIdx.x;
    int lane = tid & 63, wave = tid >> 6;
    int rp = blockIdx.x, n = blockIdx.y;
    int y0 = rp * 2;
    int l31 = lane & 31, half = lane >> 5;

    float s1 = scales[1];

    {   // per-block BN1 coeff compute from exact int64 sums
        int c = tid;
        double sc0 = (double)scales[0];
        double S  = (double)(long long)sums[c];
        double S2 = (double)(long long)sums[256 + c];
        double meanS = S / (double)NPIX;
        double varS  = S2 / (double)NPIX - meanS * meanS;
        float meanf = (float)(sc0 * meanS);
        float varf  = (float)(sc0 * sc0 * varS);
        float rstd = (float)(1.0 / sqrt((double)varf + 1e-5));
        float gc = g[c], bc = bb[c];
        a1s[c >> 4][c & 15] = (float)(sc0 * (double)rstd * (double)gc * 16.0);
        b1s[c >> 4][c & 15] = bc - meanf * rstd * gc;
    }
    __syncthreads();
    for (int i = tid; i < 4 * 58 * 16; i += 256) {
        int rr = i / (58 * 16);
        int rem = i - rr * (58 * 16);
        int px = rem >> 4, hh = rem & 15;
        int irow = y0 + rr - 1, ix = px - 1;
        v4i v = {0, 0, 0, 0};
        if ((unsigned)irow < 56u && (unsigned)ix < 56u) {
            const short* sp = CinQ + ((size_t)(n * HW + irow * 56 + ix) * 256 + hh * 16);
            v8s q0 = *(const v8s*)sp;
            v8s q1 = *(const v8s*)(sp + 8);
            unsigned wq[4] = {0, 0, 0, 0};
            #pragma unroll
            for (int j = 0; j < 16; ++j) {
                short sv = j < 8 ? q0[j] : q1[j - 8];
                float y1 = fmaf((float)sv, a1s[hh][j], b1s[hh][j]);
                y1 = fminf(fmaxf(y1, 0.f), 1.f);
                wq[j >> 2] |= (unsigned)(unsigned char)(int)rintf(y1 * 15.f) << (8 * (j & 3));
            }
            v = (v4i){(int)wq[0], (int)wq[1], (int)wq[2], (int)wq[3]};
        }
        actT[hh * 233 + rr * 58 + px] = v;
    }
    __syncthreads();   // actT read-only from here

    int c0 = wave, c1 = wave + 4;
    const char* wgb = (const char*)Wp;
    stageW(wgb, (char*)&wbuf[0][0], 0, c0, c1, lane);

    int pidx[4];
    #pragma unroll
    for (int m = 0; m < 4; ++m) {
        int s = m * 32 + l31;
        int rr = s >> 6, col = s & 63;
        int xx = col < 56 ? col : 55;
        pidx[m] = (rr + 1) * 58 + xx + 1;
    }

    v16i acc[8] = {};

    int kt = 0;
    #pragma unroll 1
    for (int dyi = 0; dyi < 3; ++dyi) {
        #pragma unroll
        for (int dxi = 0; dxi < 3; ++dxi) {
            int doff = dyi * 58 + dxi - 59;
            #pragma unroll
            for (int kk = 0; kk < 8; ++kk) {
                int ktn = kt + 1; if (ktn > 71) ktn = 71;
                stageW(wgb, (char*)&wbuf[ktn & 1][0], ktn, c0, c1, lane);
                asm volatile("s_waitcnt vmcnt(2)" ::: "memory");
                const v4i* wb = &wbuf[kt & 1][0];
                int hb = (kk * 2 + half) * 233 + doff;
                v4i wf0 = wb[c0 * 64 + lane];
                v4i wf1 = wb[c1 * 64 + lane];
                v4i af0 = actT[hb + pidx[0]];
                v4i af1 = actT[hb + pidx[1]];
                v4i af2 = actT[hb + pidx[2]];
                v4i af3 = actT[hb + pidx[3]];
                acc[0] = __builtin_amdgcn_mfma_i32_32x32x32_i8(wf0, af0, acc[0], 0, 0, 0);
                acc[1] = __builtin_amdgcn_mfma_i32_32x32x32_i8(wf0, af1, acc[1], 0, 0, 0);
                acc[2] = __builtin_amdgcn_mfma_i32_32x32x32_i8(wf0, af2, acc[2], 0, 0, 0);
                acc[3] = __builtin_amdgcn_mfma_i32_32x32x32_i8(wf0, af3, acc[3], 0, 0, 0);
                acc[4] = __builtin_amdgcn_mfma_i32_32x32x32_i8(wf1, af0, acc[4], 0, 0, 0);
                acc[5] = __builtin_amdgcn_mfma_i32_32x32x32_i8(wf1, af1, acc[5], 0, 0, 0);
                acc[6] = __builtin_amdgcn_mfma_i32_32x32x32_i8(wf1, af2, acc[6], 0, 0, 0);
                acc[7] = __builtin_amdgcn_mfma_i32_32x32x32_i8(wf1, af3, acc[7], 0, 0, 0);
                ++kt;
            }
        }
    }
    asm volatile("s_waitcnt vmcnt(0)" ::: "memory");

    #pragma unroll
    for (int m = 0; m < 4; ++m) {
        int s = m * 32 + l31;
        int rr = s >> 6, col = s & 63;
        if (col < 56) {
            size_t boff = (size_t)n * NCH * HW + (size_t)(y0 + rr) * 56 + col;
            #pragma unroll
            for (int ci = 0; ci < 2; ++ci) {
                v16i a = acc[ci * 4 + m];
                #pragma unroll
                for (int r = 0; r < 16; ++r) {
                    int prow = (r & 3) + ((r >> 2) << 3) + (half << 2);
                    int co = (wave + ci * 4) * 32 + prow;
                    size_t off = boff + (size_t)co * HW;
                    Out[off] = fmaf(s1, (float)a[r], Xin[off]);
                }
            }
        }
    }
}

// conv1 fallback: reads pre-quantized padded acts (used when ws too small)
__global__ __launch_bounds__(256, 2) void conv1_plain(const int8_t* __restrict__ A,
        const v4i* __restrict__ Wp, const float* __restrict__ scales,
        const float* __restrict__ Xin, float* __restrict__ Out) {
    __shared__ v4i actT[16 * 233];
    __shared__ v4i wbuf[2][512];
    int tid = threadIdx.x;
    int lane = tid & 63, wave = tid >> 6;
    int rp = blockIdx.x, n = blockIdx.y;
    int y0 = rp * 2;
    int l31 = lane & 31, half = lane >> 5;

    float s1 = scales[1];

    const int8_t* asrc = A + (((size_t)n * PADH + y0) * PADH) * 256;
    for (int i = tid; i < 4 * 58 * 16; i += 256) {
        int rr = i / (58 * 16);
        int rem = i - rr * (58 * 16);
        int px = rem >> 4, hh = rem & 15;
        v4i v = *(const v4i*)(asrc + ((size_t)rr * PADH + px) * 256 + hh * 16);
        actT[hh * 233 + rr * 58 + px] = v;
    }
    __syncthreads();

    int c0 = wave, c1 = wave + 4;
    const char* wgb = (const char*)Wp;
    stageW(wgb, (char*)&wbuf[0][0], 0, c0, c1, lane);

    int pidx[4];
    #pragma unroll
    for (int m = 0; m < 4; ++m) {
        int s = m * 32 + l31;
        int rr = s >> 6, col = s & 63;
        int xx = col < 56 ? col : 55;
        pidx[m] = (rr + 1) * 58 + xx + 1;
    }

    v16i acc[8] = {};

    int kt = 0;
    #pragma unroll 1
    for (int dyi = 0; dyi < 3; ++dyi) {
        #pragma unroll
        for (int dxi = 0; dxi < 3; ++dxi) {
            int doff = dyi * 58 + dxi - 59;
            #pragma unroll
            for (int kk = 0; kk < 8; ++kk) {
                int ktn = kt + 1; if (ktn > 71) ktn = 71;
                stageW(wgb, (char*)&wbuf[ktn & 1][0], ktn, c0, c1, lane);
                asm volatile("s_waitcnt vmcnt(2)" ::: "memory");
                const v4i* wb = &wbuf[kt & 1][0];
                int hb = (kk * 2 + half) * 233 + doff;
                v4i wf0 = wb[c0 * 64 + lane];
                v4i wf1 = wb[c1 * 64 + lane];
                v4i af0 = actT[hb + pidx[0]];
                v4i af1 = actT[hb + pidx[1]];
                v4i af2 = actT[hb + pidx[2]];
                v4i af3 = actT[hb + pidx[3]];
                acc[0] = __builtin_amdgcn_mfma_i32_32x32x32_i8(wf0, af0, acc[0], 0, 0, 0);
                acc[1] = __builtin_amdgcn_mfma_i32_32x32x32_i8(wf0, af1, acc[1], 0, 0, 0);
                acc[2] = __builtin_amdgcn_mfma_i32_32x32x32_i8(wf0, af2, acc[2], 0, 0, 0);
                acc[3] = __builtin_amdgcn_mfma_i32_32x32x32_i8(wf0, af3, acc[3], 0, 0, 0);
                acc[4] = __builtin_amdgcn_mfma_i32_32x32x32_i8(wf1, af0, acc[4], 0, 0, 0);
                acc[5] = __builtin_amdgcn_mfma_i32_32x32x32_i8(wf1, af1, acc[5], 0, 0, 0);
                acc[6] = __builtin_amdgcn_mfma_i32_32x32x32_i8(wf1, af2, acc[6], 0, 0, 0);
                acc[7] = __builtin_amdgcn_mfma_i32_32x32x32_i8(wf1, af3, acc[7], 0, 0, 0);
                ++kt;
            }
        }
    }
    asm volatile("s_waitcnt vmcnt(0)" ::: "memory");

    #pragma unroll
    for (int m = 0; m < 4; ++m) {
        int s = m * 32 + l31;
        int rr = s >> 6, col = s & 63;
        if (col < 56) {
            size_t boff = (size_t)n * NCH * HW + (size_t)(y0 + rr) * 56 + col;
            #pragma unroll
            for (int ci = 0; ci < 2; ++ci) {
                v16i a = acc[ci * 4 + m];
                #pragma unroll
                for (int r = 0; r < 16; ++r) {
                    int prow = (r & 3) + ((r >> 2) << 3) + (half << 2);
                    int co = (wave + ci * 4) * 32 + prow;
                    size_t off = boff + (size_t)co * HW;
                    Out[off] = fmaf(s1, (float)a[r], Xin[off]);
                }
            }
        }
    }
}

// fallback only: requantize conv0 int16 output -> padded NHWC int8
__global__ __launch_bounds__(256) void quant1(const short* __restrict__ Cin,
        const unsigned long long* __restrict__ sums, const float* __restrict__ g,
        const float* __restrict__ bb, const float* __restrict__ scales,
        int8_t* __restrict__ A) {
    __shared__ float a1s[256], b1s[256];
    int t = threadIdx.x;
    {
        double sc0 = (double)scales[0];
        double S  = (double)(long long)sums[t];
        double S2 = (double)(long long)sums[256 + t];
        double meanS = S / (double)NPIX;
        double varS  = S2 / (double)NPIX - meanS * meanS;
        float meanf = (float)(sc0 * meanS);
        float varf  = (float)(sc0 * sc0 * varS);
        float rstd = (float)(1.0 / sqrt((double)varf + 1e-5));
        float gc = g[t], bc = bb[t];
        a1s[t] = (float)(sc0 * (double)rstd * (double)gc * 16.0);
        b1s[t] = bc - meanf * rstd * gc;
    }
    __syncthreads();
    for (int idx = blockIdx.x * 256 + t; idx < NPIX * 32; idx += gridDim.x * 256) {
        int e8 = idx * 8;
        int p = e8 >> 8, c8 = e8 & 255;
        int n = p / HW, r2 = p % HW, y = r2 / 56, xx = r2 % 56;
        v8s v = *(const v8s*)(Cin + e8);
        unsigned long long w = 0;
        #pragma unroll
        for (int j = 0; j < 8; ++j) {
            float y1 = fmaf((float)v[j], a1s[c8 + j], b1s[c8 + j]);
            y1 = fminf(fmaxf(y1, 0.f), 1.f);
            w |= (unsigned long long)(unsigned char)(int)rintf(y1 * 15.f) << (8 * j);
        }
        size_t dst = (((size_t)n * PADH + y + 1) * PADH + xx + 1) * 256 + c8;
        *(unsigned long long*)(A + dst) = w;
    }
}

extern "C" void kernel_launch(void* const* d_in, const int* in_sizes, int n_in,
                              void* d_out, int out_size, void* d_ws, size_t ws_size,
                              hipStream_t stream) {
    const float* x  = (const float*)d_in[0];
    const float* g0 = (const float*)d_in[1];
    const float* b0 = (const float*)d_in[2];
    const float* w0 = (const float*)d_in[3];
    const float* g1 = (const float*)d_in[4];
    const float* b1 = (const float*)d_in[5];
    const float* w1 = (const float*)d_in[6];
    float* out = (float*)d_out;

    char* ws = (char*)d_ws;
    int8_t* a0 = (int8_t*)(ws + A0_OFF);
    v4i* wp0 = (v4i*)(ws + WP0_OFF);
    v4i* wp1 = (v4i*)(ws + WP1_OFF);
    float* coef = (float*)(ws + COEF_OFF);
    float* A0c = coef;       float* B0c = coef + 256;
    float* scales = coef + 512;              // [0]=scale0 [1]=scale1
    unsigned* maxw = (unsigned*)(ws + MAXW_OFF);
    unsigned long long* sums = (unsigned long long*)(ws + SUM1_OFF);
    double2* part = (double2*)(ws + PART_OFF);

    // fused path (quant1 eliminated) if workspace can hold int16 Cout;
    // ws_size is fixed per-harness -> branch is deterministic & capture-safe.
    bool fuse = ws_size >= (size_t)CQ_OFF + CQ_BYTES;
    short* c0 = fuse ? (short*)(ws + CQ_OFF) : (short*)d_out;

    hipMemsetAsync(ws + MAXW_OFF, 0, 32 + 4096, stream);   // maxw + sums
    aux1<<<4608, 256, 0, stream>>>(x, part, w0, w1, maxw);
    aux2<<<257, 256, 0, stream>>>(part, g0, b0, w0, w1, maxw,
                                  A0c, B0c, (int8_t*)wp0, (int8_t*)wp1, scales);
    quant0<<<dim3(56, 16), 256, 0, stream>>>(x, A0c, B0c, a0);
    conv0_mfma<<<dim3(28, 16), 256, 0, stream>>>(a0, wp0, c0, sums);
    if (fuse) {
        conv1_fused<<<dim3(28, 16), 256, 0, stream>>>(c0, wp1, sums, g1, b1,
                                                      scales, x, out);
    } else {
        quant1<<<448, 256, 0, stream>>>(c0, sums, g1, b1, scales, a0);
        conv1_plain<<<dim3(28, 16), 256, 0, stream>>>(a0, wp1, scales, x, out);
    }
}

// Round 26
// 169.222 us; speedup vs baseline: 1.0059x; 1.0018x over previous
//
#include <hip/hip_runtime.h>
#include <stdint.h>
#include <math.h>

typedef int v4i  __attribute__((ext_vector_type(4)));
typedef int v16i __attribute__((ext_vector_type(16)));
typedef short v8s __attribute__((ext_vector_type(8)));

#define NIMG 16
#define NCH  256
#define HW   3136          // 56*56
#define NPIX 50176         // 16*3136
#define PADH 58
#define NKT  72            // 2304/32
#define NCOT 8             // 256/32
#define WELEMS 589824      // 256*256*3*3

// workspace layout (bytes)
#define A0_OFF   0
#define A0_BYTES (16*58*58*256)          // 13,778,944 padded NHWC int8 acts
#define WP0_OFF  (A0_OFF + A0_BYTES)
#define WP_BYTES (NKT*NCOT*64*16)        // 589,824 packed weight frags
#define WP1_OFF  (WP0_OFF + WP_BYTES)
#define COEF_OFF (WP1_OFF + WP_BYTES)    // floats A0[256] B0[256] scales[2]
#define MAXW_OFF (COEF_OFF + 4352)       // 2 x u32   (zeroed by 4KB memset)
#define SUM1_OFF (MAXW_OFF + 32)         // 512 x u64 (zeroed by 4KB memset)
#define PART_OFF (SUM1_OFF + 4096)       // 4096 x double2 (bn0 per-plane partials)
#define CQ_OFF   15032832                // 256-aligned; optional int16 Cout here
#define CQ_BYTES ((size_t)NPIX*256*2)    // 25,690,112

// aux1: blocks 0..4095 = bn0 per-plane partial sums; blocks 4096..4607 = wmax
__global__ __launch_bounds__(256) void aux1(const float* __restrict__ X,
        double2* __restrict__ part, const float* __restrict__ W0,
        const float* __restrict__ W1, unsigned* __restrict__ maxw) {
    int b = blockIdx.x;
    int tid = threadIdx.x;
    if (b < 4096) {
        const float4* src = (const float4*)(X + (size_t)b * HW);
        double s = 0.0, s2 = 0.0;
        for (int i = tid; i < HW / 4; i += 256) {
            float4 v = src[i];
            s  += (double)v.x + (double)v.y + (double)v.z + (double)v.w;
            s2 += (double)v.x * (double)v.x + (double)v.y * (double)v.y
                + (double)v.z * (double)v.z + (double)v.w * (double)v.w;
        }
        #pragma unroll
        for (int off = 32; off; off >>= 1) {
            s  += __shfl_xor(s, off);
            s2 += __shfl_xor(s2, off);
        }
        __shared__ double sh[8];
        int wave = tid >> 6, lane = tid & 63;
        if (lane == 0) { sh[wave * 2] = s; sh[wave * 2 + 1] = s2; }
        __syncthreads();
        if (tid == 0) {
            double2 o; o.x = sh[0] + sh[2] + sh[4] + sh[6];
            o.y = sh[1] + sh[3] + sh[5] + sh[7];
            part[b] = o;
        }
    } else {
        int wb = b - 4096;                 // 0..511
        int ten = wb >> 8, blk = wb & 255;
        const float* Wt = ten ? W1 : W0;
        __shared__ float sh[256];
        float m = 0.f;
        for (int i = blk * 256 + tid; i < WELEMS; i += 256 * 256)
            m = fmaxf(m, fabsf(Wt[i]));
        sh[tid] = m; __syncthreads();
        for (int o = 128; o > 0; o >>= 1) {
            if (tid < o) sh[tid] = fmaxf(sh[tid], sh[tid + o]);
            __syncthreads();
        }
        if (tid == 0) atomicMax(&maxw[ten], __float_as_uint(sh[0]));
    }
}

// aux2: block 0 = bn0 finalize; blocks 1..256 = weight quant+pack (TAP-MAJOR,
// matching the conv: k = tap*256 + ci; Wpack[kt][cot][lane][16])
__global__ __launch_bounds__(256) void aux2(const double2* __restrict__ part,
        const float* __restrict__ g, const float* __restrict__ bb,
        const float* __restrict__ W0, const float* __restrict__ W1,
        const unsigned* __restrict__ maxwBits, float* __restrict__ A0,
        float* __restrict__ B0, int8_t* __restrict__ D0, int8_t* __restrict__ D1,
        float* __restrict__ scales) {
    int b = blockIdx.x;
    int tid = threadIdx.x;
    if (b == 0) {
        int c = tid;
        double s = 0.0, s2 = 0.0;
        for (int n = 0; n < NIMG; ++n) {
            double2 v = part[n * 256 + c];
            s += v.x; s2 += v.y;
        }
        double mean = s / (double)NPIX;
        double var  = s2 / (double)NPIX - mean * mean;
        float meanf = (float)mean, varf = (float)var;
        float rstd = (float)(1.0 / sqrt((double)varf + 1e-5));
        float gc = g[c], bc = bb[c];
        A0[c] = rstd * gc;
        B0[c] = bc - meanf * rstd * gc;
    } else {
        int wb = b - 1;                    // 0..255
        int ten = wb >> 7, blk = wb & 127;
        const float* Wt = ten ? W1 : W0;
        int8_t* dst = ten ? D1 : D0;
        float maxw = tanhf(__uint_as_float(maxwBits[ten]));
        if (blk == 0 && tid == 0) scales[ten] = maxw / 225.f;
        float twoM = 2.f * maxw;
        for (int e = blk * 256 + tid; e < WELEMS; e += 128 * 256) {
            int o = e / 2304, rem = e % 2304;
            int ci = rem / 9, tap = rem % 9;
            float t = tanhf(Wt[e]);
            float wn = t / twoM + 0.5f;
            int r = (int)rintf(wn * 15.f);
            int q = 2 * r - 15;
            int k = tap * 256 + ci;        // tap-major conv layout
            int kt = k >> 5, k5 = k & 31;
            int lane = ((k5 >> 4) << 5) | (o & 31);
            int j = k5 & 15;
            dst[((((size_t)kt * NCOT + (o >> 5)) * 64 + lane) << 4) | j] = (int8_t)q;
        }
    }
}

// quantize BN0(x) -> padded NHWC int8 via LDS transpose; one block per (n,h).
// Also writes the pad halo zeros (replaces the 13.8MB memset).
__global__ __launch_bounds__(256) void quant0(const float* __restrict__ X,
        const float* __restrict__ A0, const float* __restrict__ B0,
        int8_t* __restrict__ Apad) {
    __shared__ int8_t tile[56 * 260];     // stride 260: conflict-free byte columns
    int h = blockIdx.x, n = blockIdx.y;
    int tid = threadIdx.x;
    const float4* src4 = (const float4*)X;
    for (int i = tid; i < 256 * 14; i += 256) {
        int c = i / 14, q = i - c * 14;
        float4 v = src4[((size_t)(n * 256 + c) * HW + h * 56) / 4 + q];
        float ac = A0[c], bc = B0[c];
        float vv[4] = {v.x, v.y, v.z, v.w};
        #pragma unroll
        for (int j = 0; j < 4; ++j) {
            float y = fmaf(vv[j], ac, bc);
            y = fminf(fmaxf(y, 0.f), 1.f);
            tile[(q * 4 + j) * 260 + c] = (int8_t)(int)rintf(y * 15.f);
        }
    }
    // halo zeroing (independent of tile)
    if (h == 0) {
        unsigned* r0  = (unsigned*)(Apad + ((size_t)n * PADH + 0) * PADH * 256);
        unsigned* r57 = (unsigned*)(Apad + (((size_t)n * PADH + 57) * PADH) * 256);
        for (int i = tid; i < 58 * 64; i += 256) { r0[i] = 0u; r57[i] = 0u; }
    }
    {
        unsigned* c0p  = (unsigned*)(Apad + (((size_t)n * PADH + h + 1) * PADH + 0) * 256);
        unsigned* c57p = (unsigned*)(Apad + (((size_t)n * PADH + h + 1) * PADH + 57) * 256);
        if (tid < 64) c0p[tid] = 0u;
        else if (tid < 128) c57p[tid - 64] = 0u;
    }
    __syncthreads();
    unsigned* dst = (unsigned*)(Apad + (((size_t)n * PADH + h + 1) * PADH + 1) * 256);
    for (int i = tid; i < 56 * 64; i += 256) {
        int w = i >> 6, c4 = (i & 63) << 2;
        dst[w * 64 + (c4 >> 2)] = *(const unsigned*)&tile[w * 260 + c4];
    }
}

typedef __attribute__((address_space(1))) const unsigned int gu32;
typedef __attribute__((address_space(3))) unsigned int lu32;
__device__ __forceinline__ void gll16(const void* g, void* l) {
    __builtin_amdgcn_global_load_lds((gu32*)g, (lu32*)l, 16, 0, 0);
}

// wave w stages its own two 1KB weight chunks (cout-tiles c0, c1) of K-step ktn
__device__ __forceinline__ void stageW(const char* wgb, char* ldsbuf,
        int ktn, int c0, int c1, int lane) {
    const char* src = wgb + (size_t)ktn * 8192;
    gll16(src + c0 * 1024 + lane * 16, ldsbuf + c0 * 1024 + lane * 16);
    gll16(src + c1 * 1024 + lane * 16, ldsbuf + c1 * 1024 + lane * 16);
}

// conv0: standalone (no template coupling). Block: 4 waves, 2 image rows x
// 256 couts; barrier-free K-loop, per-wave weight chunk ownership, vmcnt(2).
// Epilogue: int16 Cout ((s+8)>>4) + fused exact int64 bn1 stats.
__global__ __launch_bounds__(256, 2) void conv0_mfma(const int8_t* __restrict__ A,
        const v4i* __restrict__ Wp, short* __restrict__ Cout,
        unsigned long long* __restrict__ sums) {
    __shared__ v4i actT[16 * 233];        // 59.6 KB, read-only after prologue
    __shared__ v4i wbuf[2][512];          // 2 x 8 KB, per-wave chunk ownership
    int tid = threadIdx.x;
    int lane = tid & 63, wave = tid >> 6;
    int rp = blockIdx.x, n = blockIdx.y;
    int y0 = rp * 2;
    int l31 = lane & 31, half = lane >> 5;

    const int8_t* asrc = A + (((size_t)n * PADH + y0) * PADH) * 256;
    for (int i = tid; i < 4 * 58 * 16; i += 256) {
        int rr = i / (58 * 16);
        int rem = i - rr * (58 * 16);
        int px = rem >> 4, hh = rem & 15;
        v4i v = *(const v4i*)(asrc + ((size_t)rr * PADH + px) * 256 + hh * 16);
        actT[hh * 233 + rr * 58 + px] = v;
    }
    __syncthreads();   // actT read-only from here

    int c0 = wave, c1 = wave + 4;
    const char* wgb = (const char*)Wp;
    stageW(wgb, (char*)&wbuf[0][0], 0, c0, c1, lane);   // W[0], own chunks

    int pidx[4];
    #pragma unroll
    for (int m = 0; m < 4; ++m) {
        int s = m * 32 + l31;
        int rr = s >> 6, col = s & 63;
        int xx = col < 56 ? col : 55;
        pidx[m] = (rr + 1) * 58 + xx + 1;
    }

    v16i acc[8] = {};

    int kt = 0;
    #pragma unroll 1
    for (int dyi = 0; dyi < 3; ++dyi) {
        #pragma unroll
        for (int dxi = 0; dxi < 3; ++dxi) {
            int doff = dyi * 58 + dxi - 59;
            #pragma unroll
            for (int kk = 0; kk < 8; ++kk) {
                int ktn = kt + 1; if (ktn > 71) ktn = 71;
                stageW(wgb, (char*)&wbuf[ktn & 1][0], ktn, c0, c1, lane);
                asm volatile("s_waitcnt vmcnt(2)" ::: "memory");
                const v4i* wb = &wbuf[kt & 1][0];
                int hb = (kk * 2 + half) * 233 + doff;
                v4i wf0 = wb[c0 * 64 + lane];
                v4i wf1 = wb[c1 * 64 + lane];
                v4i af0 = actT[hb + pidx[0]];
                v4i af1 = actT[hb + pidx[1]];
                v4i af2 = actT[hb + pidx[2]];
                v4i af3 = actT[hb + pidx[3]];
                acc[0] = __builtin_amdgcn_mfma_i32_32x32x32_i8(af0, wf0, acc[0], 0, 0, 0);
                acc[1] = __builtin_amdgcn_mfma_i32_32x32x32_i8(af1, wf0, acc[1], 0, 0, 0);
                acc[2] = __builtin_amdgcn_mfma_i32_32x32x32_i8(af2, wf0, acc[2], 0, 0, 0);
                acc[3] = __builtin_amdgcn_mfma_i32_32x32x32_i8(af3, wf0, acc[3], 0, 0, 0);
                acc[4] = __builtin_amdgcn_mfma_i32_32x32x32_i8(af0, wf1, acc[4], 0, 0, 0);
                acc[5] = __builtin_amdgcn_mfma_i32_32x32x32_i8(af1, wf1, acc[5], 0, 0, 0);
                acc[6] = __builtin_amdgcn_mfma_i32_32x32x32_i8(af2, wf1, acc[6], 0, 0, 0);
                acc[7] = __builtin_amdgcn_mfma_i32_32x32x32_i8(af3, wf1, acc[7], 0, 0, 0);
                ++kt;
            }
        }
    }
    asm volatile("s_waitcnt vmcnt(0)" ::: "memory");

    int pbase = n * HW + y0 * 56;
    #pragma unroll
    for (int ci = 0; ci < 2; ++ci) {
        int co = (wave + ci * 4) * 32 + l31;
        long long ssum = 0, ssq = 0;
        #pragma unroll
        for (int m = 0; m < 4; ++m) {
            v16i a = acc[ci * 4 + m];
            #pragma unroll
            for (int r = 0; r < 16; ++r) {
                int prow = (r & 3) + ((r >> 2) << 3) + (half << 2);
                int s = m * 32 + prow;
                int rr = s >> 6, col = s & 63;
                if (col < 56) {
                    Cout[(size_t)(pbase + rr * 56 + col) * 256 + co] =
                        (short)((a[r] + 8) >> 4);
                    ssum += a[r];
                    ssq  += (long long)a[r] * a[r];
                }
            }
        }
        ssum += __shfl_xor(ssum, 32);
        ssq  += __shfl_xor(ssq, 32);
        if (half == 0) {
            atomicAdd(&sums[co], (unsigned long long)ssum);
            atomicAdd(&sums[256 + co], (unsigned long long)ssq);
        }
    }
}

// conv1 fused: reads int16 Cout directly, computes BN1 affine per block from
// exact sums, quantizes inline during act staging. Coeffs in padded [16][17]
// LDS (bank stride 17 -> staging reads conflict-free).
__global__ __launch_bounds__(256, 2) void conv1_fused(const short* __restrict__ CinQ,
        const v4i* __restrict__ Wp, const unsigned long long* __restrict__ sums,
        const float* __restrict__ g, const float* __restrict__ bb,
        const float* __restrict__ scales, const float* __restrict__ Xin,
        float* __restrict__ Out) {
    __shared__ v4i actT[16 * 233];
    __shared__ v4i wbuf[2][512];
    __shared__ float a1s[16][17], b1s[16][17];   // +1 pad: conflict-free
    int tid = threadIdx.x;
    int lane = tid & 63, wave = tid >> 6;
    int rp = blockIdx.x, n = blockIdx.y;
    int y0 = rp * 2;
    int l31 = lane & 31, half = lane >> 5;

    float s1 = scales[1];

    {   // per-block BN1 coeff compute from exact int64 sums
        int c = tid;
        double sc0 = (double)scales[0];
        double S  = (double)(long long)sums[c];
        double S2 = (double)(long long)sums[256 + c];
        double meanS = S / (double)NPIX;
        double varS  = S2 / (double)NPIX - meanS * meanS;
        float meanf = (float)(sc0 * meanS);
        float varf  = (float)(sc0 * sc0 * varS);
        float rstd = (float)(1.0 / sqrt((double)varf + 1e-5));
        float gc = g[c], bc = bb[c];
        a1s[c >> 4][c & 15] = (float)(sc0 * (double)rstd * (double)gc * 16.0);
        b1s[c >> 4][c & 15] = bc - meanf * rstd * gc;
    }
    __syncthreads();
    for (int i = tid; i < 4 * 58 * 16; i += 256) {
        int rr = i / (58 * 16);
        int rem = i - rr * (58 * 16);
        int px = rem >> 4, hh = rem & 15;
        int irow = y0 + rr - 1, ix = px - 1;
        v4i v = {0, 0, 0, 0};
        if ((unsigned)irow < 56u && (unsigned)ix < 56u) {
            const short* sp = CinQ + ((size_t)(n * HW + irow * 56 + ix) * 256 + hh * 16);
            v8s q0 = *(const v8s*)sp;
            v8s q1 = *(const v8s*)(sp + 8);
            unsigned wq[4] = {0, 0, 0, 0};
            #pragma unroll
            for (int j = 0; j < 16; ++j) {
                short sv = j < 8 ? q0[j] : q1[j - 8];
                float y1 = fmaf((float)sv, a1s[hh][j], b1s[hh][j]);
                y1 = fminf(fmaxf(y1, 0.f), 1.f);
                wq[j >> 2] |= (unsigned)(unsigned char)(int)rintf(y1 * 15.f) << (8 * (j & 3));
            }
            v = (v4i){(int)wq[0], (int)wq[1], (int)wq[2], (int)wq[3]};
        }
        actT[hh * 233 + rr * 58 + px] = v;
    }
    __syncthreads();   // actT read-only from here

    int c0 = wave, c1 = wave + 4;
    const char* wgb = (const char*)Wp;
    stageW(wgb, (char*)&wbuf[0][0], 0, c0, c1, lane);

    int pidx[4];
    #pragma unroll
    for (int m = 0; m < 4; ++m) {
        int s = m * 32 + l31;
        int rr = s >> 6, col = s & 63;
        int xx = col < 56 ? col : 55;
        pidx[m] = (rr + 1) * 58 + xx + 1;
    }

    v16i acc[8] = {};

    int kt = 0;
    #pragma unroll 1
    for (int dyi = 0; dyi < 3; ++dyi) {
        #pragma unroll
        for (int dxi = 0; dxi < 3; ++dxi) {
            int doff = dyi * 58 + dxi - 59;
            #pragma unroll
            for (int kk = 0; kk < 8; ++kk) {
                int ktn = kt + 1; if (ktn > 71) ktn = 71;
                stageW(wgb, (char*)&wbuf[ktn & 1][0], ktn, c0, c1, lane);
                asm volatile("s_waitcnt vmcnt(2)" ::: "memory");
                const v4i* wb = &wbuf[kt & 1][0];
                int hb = (kk * 2 + half) * 233 + doff;
                v4i wf0 = wb[c0 * 64 + lane];
                v4i wf1 = wb[c1 * 64 + lane];
                v4i af0 = actT[hb + pidx[0]];
                v4i af1 = actT[hb + pidx[1]];
                v4i af2 = actT[hb + pidx[2]];
                v4i af3 = actT[hb + pidx[3]];
                acc[0] = __builtin_amdgcn_mfma_i32_32x32x32_i8(wf0, af0, acc[0], 0, 0, 0);
                acc[1] = __builtin_amdgcn_mfma_i32_32x32x32_i8(wf0, af1, acc[1], 0, 0, 0);
                acc[2] = __builtin_amdgcn_mfma_i32_32x32x32_i8(wf0, af2, acc[2], 0, 0, 0);
                acc[3] = __builtin_amdgcn_mfma_i32_32x32x32_i8(wf0, af3, acc[3], 0, 0, 0);
                acc[4] = __builtin_amdgcn_mfma_i32_32x32x32_i8(wf1, af0, acc[4], 0, 0, 0);
                acc[5] = __builtin_amdgcn_mfma_i32_32x32x32_i8(wf1, af1, acc[5], 0, 0, 0);
                acc[6] = __builtin_amdgcn_mfma_i32_32x32x32_i8(wf1, af2, acc[6], 0, 0, 0);
                acc[7] = __builtin_amdgcn_mfma_i32_32x32x32_i8(wf1, af3, acc[7], 0, 0, 0);
                ++kt;
            }
        }
    }
    asm volatile("s_waitcnt vmcnt(0)" ::: "memory");

    #pragma unroll
    for (int m = 0; m < 4; ++m) {
        int s = m * 32 + l31;
        int rr = s >> 6, col = s & 63;
        if (col < 56) {
            size_t boff = (size_t)n * NCH * HW + (size_t)(y0 + rr) * 56 + col;
            #pragma unroll
            for (int ci = 0; ci < 2; ++ci) {
                v16i a = acc[ci * 4 + m];
                #pragma unroll
                for (int r = 0; r < 16; ++r) {
                    int prow = (r & 3) + ((r >> 2) << 3) + (half << 2);
                    int co = (wave + ci * 4) * 32 + prow;
                    size_t off = boff + (size_t)co * HW;
                    Out[off] = fmaf(s1, (float)a[r], Xin[off]);
                }
            }
        }
    }
}

// conv1 fallback: reads pre-quantized padded acts (used when ws too small)
__global__ __launch_bounds__(256, 2) void conv1_plain(const int8_t* __restrict__ A,
        const v4i* __restrict__ Wp, const float* __restrict__ scales,
        const float* __restrict__ Xin, float* __restrict__ Out) {
    __shared__ v4i actT[16 * 233];
    __shared__ v4i wbuf[2][512];
    int tid = threadIdx.x;
    int lane = tid & 63, wave = tid >> 6;
    int rp = blockIdx.x, n = blockIdx.y;
    int y0 = rp * 2;
    int l31 = lane & 31, half = lane >> 5;

    float s1 = scales[1];

    const int8_t* asrc = A + (((size_t)n * PADH + y0) * PADH) * 256;
    for (int i = tid; i < 4 * 58 * 16; i += 256) {
        int rr = i / (58 * 16);
        int rem = i - rr * (58 * 16);
        int px = rem >> 4, hh = rem & 15;
        v4i v = *(const v4i*)(asrc + ((size_t)rr * PADH + px) * 256 + hh * 16);
        actT[hh * 233 + rr * 58 + px] = v;
    }
    __syncthreads();

    int c0 = wave, c1 = wave + 4;
    const char* wgb = (const char*)Wp;
    stageW(wgb, (char*)&wbuf[0][0], 0, c0, c1, lane);

    int pidx[4];
    #pragma unroll
    for (int m = 0; m < 4; ++m) {
        int s = m * 32 + l31;
        int rr = s >> 6, col = s & 63;
        int xx = col < 56 ? col : 55;
        pidx[m] = (rr + 1) * 58 + xx + 1;
    }

    v16i acc[8] = {};

    int kt = 0;
    #pragma unroll 1
    for (int dyi = 0; dyi < 3; ++dyi) {
        #pragma unroll
        for (int dxi = 0; dxi < 3; ++dxi) {
            int doff = dyi * 58 + dxi - 59;
            #pragma unroll
            for (int kk = 0; kk < 8; ++kk) {
                int ktn = kt + 1; if (ktn > 71) ktn = 71;
                stageW(wgb, (char*)&wbuf[ktn & 1][0], ktn, c0, c1, lane);
                asm volatile("s_waitcnt vmcnt(2)" ::: "memory");
                const v4i* wb = &wbuf[kt & 1][0];
                int hb = (kk * 2 + half) * 233 + doff;
                v4i wf0 = wb[c0 * 64 + lane];
                v4i wf1 = wb[c1 * 64 + lane];
                v4i af0 = actT[hb + pidx[0]];
                v4i af1 = actT[hb + pidx[1]];
                v4i af2 = actT[hb + pidx[2]];
                v4i af3 = actT[hb + pidx[3]];
                acc[0] = __builtin_amdgcn_mfma_i32_32x32x32_i8(wf0, af0, acc[0], 0, 0, 0);
                acc[1] = __builtin_amdgcn_mfma_i32_32x32x32_i8(wf0, af1, acc[1], 0, 0, 0);
                acc[2] = __builtin_amdgcn_mfma_i32_32x32x32_i8(wf0, af2, acc[2], 0, 0, 0);
                acc[3] = __builtin_amdgcn_mfma_i32_32x32x32_i8(wf0, af3, acc[3], 0, 0, 0);
                acc[4] = __builtin_amdgcn_mfma_i32_32x32x32_i8(wf1, af0, acc[4], 0, 0, 0);
                acc[5] = __builtin_amdgcn_mfma_i32_32x32x32_i8(wf1, af1, acc[5], 0, 0, 0);
                acc[6] = __builtin_amdgcn_mfma_i32_32x32x32_i8(wf1, af2, acc[6], 0, 0, 0);
                acc[7] = __builtin_amdgcn_mfma_i32_32x32x32_i8(wf1, af3, acc[7], 0, 0, 0);
                ++kt;
            }
        }
    }
    asm volatile("s_waitcnt vmcnt(0)" ::: "memory");

    #pragma unroll
    for (int m = 0; m < 4; ++m) {
        int s = m * 32 + l31;
        int rr = s >> 6, col = s & 63;
        if (col < 56) {
            size_t boff = (size_t)n * NCH * HW + (size_t)(y0 + rr) * 56 + col;
            #pragma unroll
            for (int ci = 0; ci < 2; ++ci) {
                v16i a = acc[ci * 4 + m];
                #pragma unroll
                for (int r = 0; r < 16; ++r) {
                    int prow = (r & 3) + ((r >> 2) << 3) + (half << 2);
                    int co = (wave + ci * 4) * 32 + prow;
                    size_t off = boff + (size_t)co * HW;
                    Out[off] = fmaf(s1, (float)a[r], Xin[off]);
                }
            }
        }
    }
}

// fallback only: requantize conv0 int16 output -> padded NHWC int8
__global__ __launch_bounds__(256) void quant1(const short* __restrict__ Cin,
        const unsigned long long* __restrict__ sums, const float* __restrict__ g,
        const float* __restrict__ bb, const float* __restrict__ scales,
        int8_t* __restrict__ A) {
    __shared__ float a1s[256], b1s[256];
    int t = threadIdx.x;
    {
        double sc0 = (double)scales[0];
        double S  = (double)(long long)sums[t];
        double S2 = (double)(long long)sums[256 + t];
        double meanS = S / (double)NPIX;
        double varS  = S2 / (double)NPIX - meanS * meanS;
        float meanf = (float)(sc0 * meanS);
        float varf  = (float)(sc0 * sc0 * varS);
        float rstd = (float)(1.0 / sqrt((double)varf + 1e-5));
        float gc = g[t], bc = bb[t];
        a1s[t] = (float)(sc0 * (double)rstd * (double)gc * 16.0);
        b1s[t] = bc - meanf * rstd * gc;
    }
    __syncthreads();
    for (int idx = blockIdx.x * 256 + t; idx < NPIX * 32; idx += gridDim.x * 256) {
        int e8 = idx * 8;
        int p = e8 >> 8, c8 = e8 & 255;
        int n = p / HW, r2 = p % HW, y = r2 / 56, xx = r2 % 56;
        v8s v = *(const v8s*)(Cin + e8);
        unsigned long long w = 0;
        #pragma unroll
        for (int j = 0; j < 8; ++j) {
            float y1 = fmaf((float)v[j], a1s[c8 + j], b1s[c8 + j]);
            y1 = fminf(fmaxf(y1, 0.f), 1.f);
            w |= (unsigned long long)(unsigned char)(int)rintf(y1 * 15.f) << (8 * j);
        }
        size_t dst = (((size_t)n * PADH + y + 1) * PADH + xx + 1) * 256 + c8;
        *(unsigned long long*)(A + dst) = w;
    }
}

extern "C" void kernel_launch(void* const* d_in, const int* in_sizes, int n_in,
                              void* d_out, int out_size, void* d_ws, size_t ws_size,
                              hipStream_t stream) {
    const float* x  = (const float*)d_in[0];
    const float* g0 = (const float*)d_in[1];
    const float* b0 = (const float*)d_in[2];
    const float* w0 = (const float*)d_in[3];
    const float* g1 = (const float*)d_in[4];
    const float* b1 = (const float*)d_in[5];
    const float* w1 = (const float*)d_in[6];
    float* out = (float*)d_out;

    char* ws = (char*)d_ws;
    int8_t* a0 = (int8_t*)(ws + A0_OFF);
    v4i* wp0 = (v4i*)(ws + WP0_OFF);
    v4i* wp1 = (v4i*)(ws + WP1_OFF);
    float* coef = (float*)(ws + COEF_OFF);
    float* A0c = coef;       float* B0c = coef + 256;
    float* scales = coef + 512;              // [0]=scale0 [1]=scale1
    unsigned* maxw = (unsigned*)(ws + MAXW_OFF);
    unsigned long long* sums = (unsigned long long*)(ws + SUM1_OFF);
    double2* part = (double2*)(ws + PART_OFF);

    // fused path (quant1 eliminated) if workspace can hold int16 Cout;
    // ws_size is fixed per-harness -> branch is deterministic & capture-safe.
    bool fuse = ws_size >= (size_t)CQ_OFF + CQ_BYTES;
    short* c0 = fuse ? (short*)(ws + CQ_OFF) : (short*)d_out;

    hipMemsetAsync(ws + MAXW_OFF, 0, 32 + 4096, stream);   // maxw + sums
    aux1<<<4608, 256, 0, stream>>>(x, part, w0, w1, maxw);
    aux2<<<257, 256, 0, stream>>>(part, g0, b0, w0, w1, maxw,
                                  A0c, B0c, (int8_t*)wp0, (int8_t*)wp1, scales);
    quant0<<<dim3(56, 16), 256, 0, stream>>>(x, A0c, B0c, a0);
    conv0_mfma<<<dim3(28, 16), 256, 0, stream>>>(a0, wp0, c0, sums);
    if (fuse) {
        conv1_fused<<<dim3(28, 16), 256, 0, stream>>>(c0, wp1, sums, g1, b1,
                                                      scales, x, out);
    } else {
        quant1<<<448, 256, 0, stream>>>(c0, sums, g1, b1, scales, a0);
        conv1_plain<<<dim3(28, 16), 256, 0, stream>>>(a0, wp1, scales, x, out);
    }
}